// Round 1
// baseline (1376.167 us; speedup 1.0000x reference)
//
#include <hip/hip_runtime.h>
#include <hip/hip_bf16.h>

#define B_ 8
#define C_ 2048
#define L_ 256
#define E_ 768
#define H_ 4
#define D_ 64
#define M_ (B_*C_)   // 16384 rows

// Block-wide reduce of (sum, sumsq). 256 threads = 4 waves.
__device__ __forceinline__ float2 block_reduce2(float2 v, float2* red, int tid) {
  #pragma unroll
  for (int off = 32; off; off >>= 1) {
    v.x += __shfl_down(v.x, off);
    v.y += __shfl_down(v.y, off);
  }
  __syncthreads();                       // protect red[] from previous round
  if ((tid & 63) == 0) red[tid >> 6] = v;
  __syncthreads();
  float2 a = red[0], b = red[1], c = red[2], d = red[3];
  return make_float2(a.x + b.x + c.x + d.x, a.y + b.y + c.y + d.y);
}

// y = LayerNorm(x @ W1 + b1) * g1 + beta1     x:[M,256] W1:[256,768] y:[M,768]
// 8 rows per block; thread owns columns {tid, tid+256, tid+512}.
__global__ __launch_bounds__(256) void gemm1_ln_kernel(
    const float* __restrict__ x, const float* __restrict__ W1,
    const float* __restrict__ b1, const float* __restrict__ g1,
    const float* __restrict__ be1, float* __restrict__ y) {
  __shared__ float xs[8][L_];
  __shared__ float2 red[4];
  const int tid = threadIdx.x;
  const int row0 = blockIdx.x * 8;
  #pragma unroll
  for (int i = 0; i < 8; ++i)
    xs[i][tid] = x[(row0 + i) * L_ + tid];
  __syncthreads();

  float acc0[8], acc1[8], acc2[8];
  #pragma unroll
  for (int r = 0; r < 8; ++r) acc0[r] = acc1[r] = acc2[r] = 0.f;

  const float* w = W1 + tid;
  for (int k = 0; k < L_; ++k) {
    float w0 = w[0], w1 = w[256], w2 = w[512];
    w += E_;
    #pragma unroll
    for (int r = 0; r < 8; ++r) {
      float xv = xs[r][k];                 // LDS broadcast (uniform addr)
      acc0[r] = fmaf(xv, w0, acc0[r]);
      acc1[r] = fmaf(xv, w1, acc1[r]);
      acc2[r] = fmaf(xv, w2, acc2[r]);
    }
  }

  const float bb0 = b1[tid], bb1 = b1[256+tid], bb2 = b1[512+tid];
  const float gg0 = g1[tid], gg1 = g1[256+tid], gg2 = g1[512+tid];
  const float ee0 = be1[tid], ee1 = be1[256+tid], ee2 = be1[512+tid];
  for (int r = 0; r < 8; ++r) {
    float v0 = acc0[r] + bb0, v1 = acc1[r] + bb1, v2 = acc2[r] + bb2;
    float2 s = block_reduce2(make_float2(v0 + v1 + v2,
                                         v0*v0 + v1*v1 + v2*v2), red, tid);
    float mu  = s.x * (1.f / E_);
    float var = s.y * (1.f / E_) - mu * mu;
    float rs  = rsqrtf(var + 1e-5f);
    float* yr = y + (row0 + r) * E_;
    yr[tid]       = (v0 - mu) * rs * gg0 + ee0;
    yr[256 + tid] = (v1 - mu) * rs * gg1 + ee1;
    yr[512 + tid] = (v2 - mu) * rs * gg2 + ee2;
  }
}

// Flash attention, f32. Grid: x = q-tile (32), y = b*H + h (32).
// Block 256 thr: row r = tid>>2 (64 q rows), quad lane owns 16 of 64 dims.
__global__ __launch_bounds__(256) void attn_kernel(const float* __restrict__ y,
                                                   float* __restrict__ o) {
  __shared__ float Ks[64][68];   // +4 pad keeps float4 rows 16B-aligned, spreads banks
  __shared__ float Vs[64][68];
  const int tid = threadIdx.x;
  const int qt = blockIdx.x;
  const int bh = blockIdx.y;
  const int b = bh >> 2, h = bh & 3;
  const int r  = tid >> 2;
  const int qd = (tid & 3) << 4;          // 0,16,32,48
  const int cq = qt * 64 + r;
  const int ybase = b * C_ * E_;

  const float* qp = y + ybase + cq * E_ + h * D_ + qd;
  const float4 Q0 = ((const float4*)qp)[0];
  const float4 Q1 = ((const float4*)qp)[1];
  const float4 Q2 = ((const float4*)qp)[2];
  const float4 Q3 = ((const float4*)qp)[3];

  float m = -3.0e38f, l = 0.f;
  float4 O0 = {0,0,0,0}, O1 = {0,0,0,0}, O2 = {0,0,0,0}, O3 = {0,0,0,0};

  for (int kt = 0; kt < 32; ++kt) {
    __syncthreads();
    #pragma unroll
    for (int i = 0; i < 4; ++i) {          // stage K,V tiles (64x64 each)
      int linear = tid + i * 256;          // float4 index in 64x16 grid
      int rr = linear >> 4;
      int dd = (linear & 15) << 2;
      const float* kp = y + ybase + (kt * 64 + rr) * E_ + 256 + h * D_ + dd;
      *(float4*)&Ks[rr][dd] = *(const float4*)kp;
      *(float4*)&Vs[rr][dd] = *(const float4*)(kp + 256);
    }
    __syncthreads();

    float s[64];
    #pragma unroll
    for (int kk = 0; kk < 64; ++kk) {      // S = Q.K^T / 8
      const float4* kr = (const float4*)&Ks[kk][qd];
      float4 a0 = kr[0], a1 = kr[1], a2 = kr[2], a3 = kr[3];
      float t;
      t  = Q0.x*a0.x + Q0.y*a0.y + Q0.z*a0.z + Q0.w*a0.w;
      t += Q1.x*a1.x + Q1.y*a1.y + Q1.z*a1.z + Q1.w*a1.w;
      t += Q2.x*a2.x + Q2.y*a2.y + Q2.z*a2.z + Q2.w*a2.w;
      t += Q3.x*a3.x + Q3.y*a3.y + Q3.z*a3.z + Q3.w*a3.w;
      t += __shfl_xor(t, 1);               // quad reduce -> full dot in all 4 lanes
      t += __shfl_xor(t, 2);
      s[kk] = t * 0.125f;
    }

    float tmax = s[0];
    #pragma unroll
    for (int kk = 1; kk < 64; ++kk) tmax = fmaxf(tmax, s[kk]);
    float mnew = fmaxf(m, tmax);
    float corr = __expf(m - mnew);
    float lsum = 0.f;
    #pragma unroll
    for (int kk = 0; kk < 64; ++kk) {
      float p = __expf(s[kk] - mnew);
      s[kk] = p;
      lsum += p;
    }
    l = l * corr + lsum;
    m = mnew;
    O0.x*=corr; O0.y*=corr; O0.z*=corr; O0.w*=corr;
    O1.x*=corr; O1.y*=corr; O1.z*=corr; O1.w*=corr;
    O2.x*=corr; O2.y*=corr; O2.z*=corr; O2.w*=corr;
    O3.x*=corr; O3.y*=corr; O3.z*=corr; O3.w*=corr;

    #pragma unroll
    for (int kk = 0; kk < 64; ++kk) {      // O += P.V
      float p = s[kk];
      const float4* vr = (const float4*)&Vs[kk][qd];
      float4 v0 = vr[0], v1 = vr[1], v2 = vr[2], v3 = vr[3];
      O0.x += p*v0.x; O0.y += p*v0.y; O0.z += p*v0.z; O0.w += p*v0.w;
      O1.x += p*v1.x; O1.y += p*v1.y; O1.z += p*v1.z; O1.w += p*v1.w;
      O2.x += p*v2.x; O2.y += p*v2.y; O2.z += p*v2.z; O2.w += p*v2.w;
      O3.x += p*v3.x; O3.y += p*v3.y; O3.z += p*v3.z; O3.w += p*v3.w;
    }
  }

  const float inv = 1.f / l;
  O0.x*=inv; O0.y*=inv; O0.z*=inv; O0.w*=inv;
  O1.x*=inv; O1.y*=inv; O1.z*=inv; O1.w*=inv;
  O2.x*=inv; O2.y*=inv; O2.z*=inv; O2.w*=inv;
  O3.x*=inv; O3.y*=inv; O3.z*=inv; O3.w*=inv;
  float* op = o + (b * C_ + cq) * L_ + h * D_ + qd;
  ((float4*)op)[0] = O0;
  ((float4*)op)[1] = O1;
  ((float4*)op)[2] = O2;
  ((float4*)op)[3] = O3;
}

// out = LayerNorm(o @ W2 + b2) * g2 + beta2 + x    all [M,256]
__global__ __launch_bounds__(256) void gemm2_ln_kernel(
    const float* __restrict__ o, const float* __restrict__ W2,
    const float* __restrict__ b2, const float* __restrict__ g2,
    const float* __restrict__ be2, const float* __restrict__ x,
    float* __restrict__ out) {
  __shared__ float os[8][L_];
  __shared__ float2 red[4];
  const int tid = threadIdx.x;
  const int row0 = blockIdx.x * 8;
  #pragma unroll
  for (int i = 0; i < 8; ++i)
    os[i][tid] = o[(row0 + i) * L_ + tid];
  __syncthreads();

  float acc[8];
  #pragma unroll
  for (int r = 0; r < 8; ++r) acc[r] = 0.f;
  const float* w = W2 + tid;
  for (int k = 0; k < L_; ++k) {
    float wv = w[0];
    w += L_;
    #pragma unroll
    for (int r = 0; r < 8; ++r) acc[r] = fmaf(os[r][k], wv, acc[r]);
  }

  const float bb = b2[tid], gg = g2[tid], ee = be2[tid];
  for (int r = 0; r < 8; ++r) {
    float v = acc[r] + bb;
    float2 s = block_reduce2(make_float2(v, v * v), red, tid);
    float mu  = s.x * (1.f / L_);
    float var = s.y * (1.f / L_) - mu * mu;
    float rs  = rsqrtf(var + 1e-5f);
    int idx = (row0 + r) * L_ + tid;
    out[idx] = (v - mu) * rs * gg + ee + x[idx];
  }
}

extern "C" void kernel_launch(void* const* d_in, const int* in_sizes, int n_in,
                              void* d_out, int out_size, void* d_ws, size_t ws_size,
                              hipStream_t stream) {
  const float* x   = (const float*)d_in[0];
  const float* W1  = (const float*)d_in[1];
  const float* b1  = (const float*)d_in[2];
  const float* g1  = (const float*)d_in[3];
  const float* be1 = (const float*)d_in[4];
  const float* W2  = (const float*)d_in[5];
  const float* b2  = (const float*)d_in[6];
  const float* g2  = (const float*)d_in[7];
  const float* be2 = (const float*)d_in[8];
  float* out = (float*)d_out;

  float* y = (float*)d_ws;                    // [M, 768] f32 = 50.3 MB
  float* o = y + (size_t)M_ * E_;             // [M, 256] f32 = 16.8 MB

  gemm1_ln_kernel<<<M_ / 8, 256, 0, stream>>>(x, W1, b1, g1, be1, y);
  attn_kernel<<<dim3(32, 32), 256, 0, stream>>>(y, o);
  gemm2_ln_kernel<<<M_ / 8, 256, 0, stream>>>(o, W2, b2, g2, be2, x, out);
}

// Round 2
// 244.628 us; speedup vs baseline: 5.6255x; 5.6255x over previous
//
#include <hip/hip_runtime.h>
#include <hip/hip_bf16.h>

#define B_ 8
#define C_ 2048
#define L_ 256
#define E_ 768
#define H_ 4
#define D_ 64
#define M_ (B_*C_)   // 16384 rows

typedef __attribute__((ext_vector_type(8))) short short8v;   // 8 bf16 (4 VGPR) MFMA A/B frag
typedef __attribute__((ext_vector_type(4))) short short4v;   // 8B packed store
typedef __attribute__((ext_vector_type(4))) float f32x4;     // MFMA C/D frag

__device__ __forceinline__ short f2bf(float f) {             // f32 -> bf16 RNE
  union { float f; unsigned u; } v; v.f = f;
  unsigned r = v.u + 0x7FFFu + ((v.u >> 16) & 1u);
  return (short)(r >> 16);
}

// Block-wide reduce of (sum, sumsq). 256 threads = 4 waves.
__device__ __forceinline__ float2 block_reduce2(float2 v, float2* red, int tid) {
  #pragma unroll
  for (int off = 32; off; off >>= 1) {
    v.x += __shfl_down(v.x, off);
    v.y += __shfl_down(v.y, off);
  }
  __syncthreads();
  if ((tid & 63) == 0) red[tid >> 6] = v;
  __syncthreads();
  float2 a = red[0], b = red[1], c = red[2], d = red[3];
  return make_float2(a.x + b.x + c.x + d.x, a.y + b.y + c.y + d.y);
}

// y = LN(x@W1+b1)*g1+beta1, emitted directly as bf16 Q (pre-scaled 1/8),
// K row-major [bh][c][64], and V transposed [bh][64][c].
__global__ __launch_bounds__(256) void gemm1_ln_kernel(
    const float* __restrict__ x, const float* __restrict__ W1,
    const float* __restrict__ b1, const float* __restrict__ g1,
    const float* __restrict__ be1,
    short* __restrict__ Qg, short* __restrict__ Kg, short* __restrict__ Vtg) {
  __shared__ float xs[8][L_];
  __shared__ float2 red[4];
  const int tid = threadIdx.x;
  const int row0 = blockIdx.x * 8;
  #pragma unroll
  for (int i = 0; i < 8; ++i)
    xs[i][tid] = x[(row0 + i) * L_ + tid];
  __syncthreads();

  float acc0[8], acc1[8], acc2[8];
  #pragma unroll
  for (int r = 0; r < 8; ++r) acc0[r] = acc1[r] = acc2[r] = 0.f;

  const float* w = W1 + tid;
  for (int k = 0; k < L_; ++k) {
    float w0 = w[0], w1 = w[256], w2 = w[512];
    w += E_;
    #pragma unroll
    for (int r = 0; r < 8; ++r) {
      float xv = xs[r][k];
      acc0[r] = fmaf(xv, w0, acc0[r]);
      acc1[r] = fmaf(xv, w1, acc1[r]);
      acc2[r] = fmaf(xv, w2, acc2[r]);
    }
  }

  const float bb0 = b1[tid], bb1 = b1[256+tid], bb2 = b1[512+tid];
  const float gg0 = g1[tid], gg1 = g1[256+tid], gg2 = g1[512+tid];
  const float ee0 = be1[tid], ee1 = be1[256+tid], ee2 = be1[512+tid];

  const int h = tid >> 6, d = tid & 63;
  const int b = row0 >> 11, cq0 = row0 & (C_ - 1);
  const size_t qkBase = ((size_t)(b*H_ + h) * C_ + cq0) * D_ + d;
  short vpack[8];

  for (int r = 0; r < 8; ++r) {
    float v0 = acc0[r] + bb0, v1 = acc1[r] + bb1, v2 = acc2[r] + bb2;
    float2 s = block_reduce2(make_float2(v0 + v1 + v2,
                                         v0*v0 + v1*v1 + v2*v2), red, tid);
    float mu  = s.x * (1.f / E_);
    float var = s.y * (1.f / E_) - mu * mu;
    float rs  = rsqrtf(var + 1e-5f);
    float qv = (v0 - mu) * rs * gg0 + ee0;
    float kv = (v1 - mu) * rs * gg1 + ee1;
    float vv = (v2 - mu) * rs * gg2 + ee2;
    Qg[qkBase + (size_t)r * D_] = f2bf(qv * 0.125f);   // fold 1/sqrt(D) here
    Kg[qkBase + (size_t)r * D_] = f2bf(kv);
    vpack[r] = f2bf(vv);
  }
  // thread owns 8 consecutive seq positions of its (h,d) column: free transpose
  *(short8v*)&Vtg[((size_t)(b*H_ + h) * D_ + d) * C_ + cq0] = *(short8v*)vpack;
}

// MFMA flash attention. Grid (32 qtiles, 32 bh), 256 thr = 4 waves,
// wave owns 16 q rows. Swapped QK^T (S^T = K.Q^T) for cheap softmax rows.
__global__ __launch_bounds__(256, 4) void attn_mfma_kernel(
    const short* __restrict__ Qg, const short* __restrict__ Kg,
    const short* __restrict__ Vtg, float* __restrict__ o) {
  __shared__ short Ks[64*72];      // [key][d], 144B rows: 16B-aligned, 2-way banks
  __shared__ short Vs[64*72];      // [d][key] (pre-transposed in gemm1)
  __shared__ short Ps[4][16*72];   // per-wave P tile [q][key]
  const int tid = threadIdx.x;
  const int w  = tid >> 6;
  const int l  = tid & 63, lo = l & 15, hi = l >> 4;
  const int qt = blockIdx.x, bh = blockIdx.y;
  const size_t hd = (size_t)bh * (C_ * D_);
  const int q0 = qt * 64 + w * 16;

  // B-frag of Q^T: lane holds Q[q0+lo][k], k = hi*8..+7 (per 32-wide k-frag)
  const short8v bq0 = *(const short8v*)(Qg + hd + (size_t)(q0+lo)*D_ + hi*8);
  const short8v bq1 = *(const short8v*)(Qg + hd + (size_t)(q0+lo)*D_ + 32 + hi*8);

  float mrun = -3.0e38f, lrun = 0.f;
  f32x4 Oacc[4] = {{0,0,0,0},{0,0,0,0},{0,0,0,0},{0,0,0,0}};
  short* Pw = &Ps[w][0];

  for (int kt = 0; kt < 32; ++kt) {
    __syncthreads();                       // prev iter's K/V reads done
    #pragma unroll
    for (int i = 0; i < 2; ++i) {          // stage K,Vt tiles (64x64 bf16 each)
      int id = tid + i * 256;
      int row = id >> 3, c8 = (id & 7) * 8;
      *(short8v*)&Ks[row*72 + c8] =
          *(const short8v*)(Kg + hd + (size_t)(kt*64 + row)*D_ + c8);
      *(short8v*)&Vs[row*72 + c8] =
          *(const short8v*)(Vtg + hd + (size_t)row*C_ + kt*64 + c8);
    }
    __syncthreads();

    // S^T tiles: D[key_local][q] ; key_local = mt*16 + hi*4 + reg, q = q0+lo
    f32x4 st[4];
    #pragma unroll
    for (int mt = 0; mt < 4; ++mt) {
      short8v ka = *(short8v*)&Ks[(mt*16 + lo)*72 + hi*8];
      short8v kb = *(short8v*)&Ks[(mt*16 + lo)*72 + 32 + hi*8];
      f32x4 z = {0.f, 0.f, 0.f, 0.f};
      z      = __builtin_amdgcn_mfma_f32_16x16x32_bf16(ka, bq0, z, 0, 0, 0);
      st[mt] = __builtin_amdgcn_mfma_f32_16x16x32_bf16(kb, bq1, z, 0, 0, 0);
    }

    // online softmax; lane handles q=lo, its 16 of 64 keys
    float ps[16];
    float tmax = -3.0e38f;
    #pragma unroll
    for (int mt = 0; mt < 4; ++mt)
      #pragma unroll
      for (int r = 0; r < 4; ++r) {
        float v = st[mt][r];
        ps[mt*4 + r] = v;
        tmax = fmaxf(tmax, v);
      }
    tmax = fmaxf(tmax, __shfl_xor(tmax, 16));
    tmax = fmaxf(tmax, __shfl_xor(tmax, 32));
    float mnew = fmaxf(mrun, tmax);
    float corr = __expf(mrun - mnew);
    mrun = mnew;
    float ll = 0.f;
    #pragma unroll
    for (int i = 0; i < 16; ++i) {
      float p = __expf(ps[i] - mnew);
      ps[i] = p;
      ll += p;
    }
    ll += __shfl_xor(ll, 16);
    ll += __shfl_xor(ll, 32);
    lrun = lrun * corr + ll;

    // corr lives in lanes keyed by q=lo; O rows are q=hi*4+reg -> transpose bcast
    float cc[4];
    #pragma unroll
    for (int r = 0; r < 4; ++r) cc[r] = __shfl(corr, hi*4 + r);
    #pragma unroll
    for (int nt = 0; nt < 4; ++nt)
      #pragma unroll
      for (int r = 0; r < 4; ++r) Oacc[nt][r] *= cc[r];

    // P (bf16) -> per-wave LDS [q][key]; 4 consecutive keys per packed store
    #pragma unroll
    for (int mt = 0; mt < 4; ++mt) {
      short4v pk;
      pk[0] = f2bf(ps[mt*4+0]); pk[1] = f2bf(ps[mt*4+1]);
      pk[2] = f2bf(ps[mt*4+2]); pk[3] = f2bf(ps[mt*4+3]);
      *(short4v*)&Pw[lo*72 + mt*16 + hi*4] = pk;
    }
    // same-wave LDS RAW: drain ds_writes before frag reads (no block barrier needed)
    asm volatile("s_waitcnt lgkmcnt(0)" ::: "memory");

    // O += P.V : A-frag from P rows, B-frag from Vt rows (both contiguous b128)
    short8v pa0 = *(short8v*)&Pw[lo*72 + hi*8];
    short8v pa1 = *(short8v*)&Pw[lo*72 + 32 + hi*8];
    #pragma unroll
    for (int nt = 0; nt < 4; ++nt) {
      short8v vb0 = *(short8v*)&Vs[(nt*16 + lo)*72 + hi*8];
      short8v vb1 = *(short8v*)&Vs[(nt*16 + lo)*72 + 32 + hi*8];
      Oacc[nt] = __builtin_amdgcn_mfma_f32_16x16x32_bf16(pa0, vb0, Oacc[nt], 0,0,0);
      Oacc[nt] = __builtin_amdgcn_mfma_f32_16x16x32_bf16(pa1, vb1, Oacc[nt], 0,0,0);
    }
  }

  float linv = 1.f / lrun;
  float li[4];
  #pragma unroll
  for (int r = 0; r < 4; ++r) li[r] = __shfl(linv, hi*4 + r);
  const int b = bh >> 2, h = bh & 3;
  float* ob = o + (size_t)(b*C_ + q0) * L_ + h*D_;
  #pragma unroll
  for (int nt = 0; nt < 4; ++nt)
    #pragma unroll
    for (int r = 0; r < 4; ++r)
      ob[(hi*4 + r) * L_ + nt*16 + lo] = Oacc[nt][r] * li[r];
}

// out = LN(o @ W2 + b2)*g2 + beta2 + x    all [M,256]
__global__ __launch_bounds__(256) void gemm2_ln_kernel(
    const float* __restrict__ o, const float* __restrict__ W2,
    const float* __restrict__ b2, const float* __restrict__ g2,
    const float* __restrict__ be2, const float* __restrict__ x,
    float* __restrict__ out) {
  __shared__ float os[8][L_];
  __shared__ float2 red[4];
  const int tid = threadIdx.x;
  const int row0 = blockIdx.x * 8;
  #pragma unroll
  for (int i = 0; i < 8; ++i)
    os[i][tid] = o[(row0 + i) * L_ + tid];
  __syncthreads();

  float acc[8];
  #pragma unroll
  for (int r = 0; r < 8; ++r) acc[r] = 0.f;
  const float* w = W2 + tid;
  for (int k = 0; k < L_; ++k) {
    float wv = w[0];
    w += L_;
    #pragma unroll
    for (int r = 0; r < 8; ++r) acc[r] = fmaf(os[r][k], wv, acc[r]);
  }

  const float bb = b2[tid], gg = g2[tid], ee = be2[tid];
  for (int r = 0; r < 8; ++r) {
    float v = acc[r] + bb;
    float2 s = block_reduce2(make_float2(v, v * v), red, tid);
    float mu  = s.x * (1.f / L_);
    float var = s.y * (1.f / L_) - mu * mu;
    float rs  = rsqrtf(var + 1e-5f);
    int idx = (row0 + r) * L_ + tid;
    out[idx] = (v - mu) * rs * gg + ee + x[idx];
  }
}

extern "C" void kernel_launch(void* const* d_in, const int* in_sizes, int n_in,
                              void* d_out, int out_size, void* d_ws, size_t ws_size,
                              hipStream_t stream) {
  const float* x   = (const float*)d_in[0];
  const float* W1  = (const float*)d_in[1];
  const float* b1  = (const float*)d_in[2];
  const float* g1  = (const float*)d_in[3];
  const float* be1 = (const float*)d_in[4];
  const float* W2  = (const float*)d_in[5];
  const float* b2  = (const float*)d_in[6];
  const float* g2  = (const float*)d_in[7];
  const float* be2 = (const float*)d_in[8];
  float* out = (float*)d_out;

  const size_t HDSZ = (size_t)B_ * H_ * C_ * D_;   // 4,194,304 elems
  short* Qg  = (short*)d_ws;                        // bf16 [bh][c][64] (pre-scaled)
  short* Kg  = Qg + HDSZ;                           // bf16 [bh][c][64]
  short* Vtg = Kg + HDSZ;                           // bf16 [bh][64][c]
  float* o   = (float*)(Vtg + HDSZ);                // f32  [M][256]

  gemm1_ln_kernel<<<M_ / 8, 256, 0, stream>>>(x, W1, b1, g1, be1, Qg, Kg, Vtg);
  attn_mfma_kernel<<<dim3(32, 32), 256, 0, stream>>>(Qg, Kg, Vtg, o);
  gemm2_ln_kernel<<<M_ / 8, 256, 0, stream>>>(o, W2, b2, g2, be2, x, out);
}

// Round 3
// 144.573 us; speedup vs baseline: 9.5188x; 1.6921x over previous
//
#include <hip/hip_runtime.h>
#include <hip/hip_bf16.h>

#define B_ 8
#define C_ 2048
#define L_ 256
#define E_ 768
#define H_ 4
#define D_ 64
#define M_ (B_*C_)   // 16384 rows

typedef __attribute__((ext_vector_type(8))) short short8v;   // 8 bf16 (4 VGPR) MFMA A/B frag
typedef __attribute__((ext_vector_type(4))) short short4v;   // 8B packed store
typedef __attribute__((ext_vector_type(4))) float f32x4;     // MFMA C/D frag

__device__ __forceinline__ short f2bf(float f) {             // f32 -> bf16 RNE
  union { float f; unsigned u; } v; v.f = f;
  unsigned r = v.u + 0x7FFFu + ((v.u >> 16) & 1u);
  return (short)(r >> 16);
}
__device__ __forceinline__ float bf2f(short s) {
  union { unsigned u; float f; } v; v.u = ((unsigned)(unsigned short)s) << 16;
  return v.f;
}

// ---- prep: x f32 -> bf16 (same layout) ----
__global__ __launch_bounds__(256) void cvt_x_kernel(const float* __restrict__ x,
                                                    short* __restrict__ xb) {
  int id = blockIdx.x * 256 + threadIdx.x;
  const float4* src = (const float4*)x + (size_t)id * 2;
  float4 a = src[0], b = src[1];
  short8v p;
  p[0]=f2bf(a.x); p[1]=f2bf(a.y); p[2]=f2bf(a.z); p[3]=f2bf(a.w);
  p[4]=f2bf(b.x); p[5]=f2bf(b.y); p[6]=f2bf(b.z); p[7]=f2bf(b.w);
  *(short8v*)(xb + (size_t)id * 8) = p;
}

// ---- prep: W f32 [K][N] -> Wt bf16 [N][K] via 32x32 LDS tiles ----
__global__ __launch_bounds__(256) void transpose_w_kernel(const float* __restrict__ W,
                                                          short* __restrict__ Wt,
                                                          int K, int N) {
  __shared__ float ld[32][33];
  const int k0 = blockIdx.x * 32, n0 = blockIdx.y * 32;
  const int tx = threadIdx.x & 31, ty = threadIdx.x >> 5;   // ty 0..7
  #pragma unroll
  for (int j = 0; j < 4; ++j)
    ld[ty + j*8][tx] = W[(size_t)(k0 + ty + j*8) * N + n0 + tx];
  __syncthreads();
  const int r  = threadIdx.x >> 3;        // n_local 0..31
  const int c0 = (threadIdx.x & 7) * 4;   // k_local
  short4v o;
  o[0]=f2bf(ld[c0+0][r]); o[1]=f2bf(ld[c0+1][r]);
  o[2]=f2bf(ld[c0+2][r]); o[3]=f2bf(ld[c0+3][r]);
  *(short4v*)(Wt + (size_t)(n0 + r) * K + k0 + c0) = o;
}

// ---- GEMM1: y1[M][768] = xb[M][256] @ W1 (+b1), bf16 MFMA, 128x128 tile ----
__global__ __launch_bounds__(256) void gemm1_mfma_kernel(
    const short* __restrict__ xb, const short* __restrict__ W1t,
    const float* __restrict__ b1, short* __restrict__ y1) {
  __shared__ short As[128*72];   // [row][64k + 8 pad]: 144B rows -> 2-way banks (free)
  __shared__ short Bs[128*72];   // rows of W1t (col-major W1)
  const int tid = threadIdx.x;
  const int w = tid >> 6, l = tid & 63, lo = l & 15, hi = l >> 4;
  const int wr = w >> 1, wc = w & 1;
  const int m0 = blockIdx.x * 128, n0 = blockIdx.y * 128;

  f32x4 acc[4][4];
  #pragma unroll
  for (int m = 0; m < 4; ++m)
    #pragma unroll
    for (int n = 0; n < 4; ++n) acc[m][n] = (f32x4){0.f,0.f,0.f,0.f};

  for (int kt = 0; kt < 4; ++kt) {
    __syncthreads();
    #pragma unroll
    for (int i = 0; i < 4; ++i) {          // 1024 chunks each tile
      int id = tid + i * 256;
      int row = id >> 3, k8 = (id & 7) * 8;
      *(short8v*)&As[row*72 + k8] =
          *(const short8v*)(xb + (size_t)(m0 + row) * 256 + kt*64 + k8);
      *(short8v*)&Bs[row*72 + k8] =
          *(const short8v*)(W1t + (size_t)(n0 + row) * 256 + kt*64 + k8);
    }
    __syncthreads();
    #pragma unroll
    for (int kk = 0; kk < 2; ++kk) {
      short8v af[4], bf[4];
      #pragma unroll
      for (int m = 0; m < 4; ++m)
        af[m] = *(short8v*)&As[(wr*64 + m*16 + lo)*72 + kk*32 + hi*8];
      #pragma unroll
      for (int n = 0; n < 4; ++n)
        bf[n] = *(short8v*)&Bs[(wc*64 + n*16 + lo)*72 + kk*32 + hi*8];
      #pragma unroll
      for (int m = 0; m < 4; ++m)
        #pragma unroll
        for (int n = 0; n < 4; ++n)
          acc[m][n] = __builtin_amdgcn_mfma_f32_16x16x32_bf16(af[m], bf[n], acc[m][n], 0,0,0);
    }
  }

  float bb[4];
  #pragma unroll
  for (int n = 0; n < 4; ++n) bb[n] = b1[n0 + wc*64 + n*16 + lo];
  #pragma unroll
  for (int m = 0; m < 4; ++m) {
    const int gr = m0 + wr*64 + m*16 + hi*4;
    #pragma unroll
    for (int r = 0; r < 4; ++r) {
      short* yp = y1 + (size_t)(gr + r) * E_ + n0 + wc*64;
      #pragma unroll
      for (int n = 0; n < 4; ++n)
        yp[n*16 + lo] = f2bf(acc[m][n][r] + bb[n]);
    }
  }
}

// ---- LN1: y1 -> Q (x0.125), K, Vt(bf16, transposed via LDS). 64 rows/block ----
__global__ __launch_bounds__(256) void ln1_kernel(
    const short* __restrict__ y1, const float* __restrict__ g1,
    const float* __restrict__ be1,
    short* __restrict__ Qg, short* __restrict__ Kg, short* __restrict__ Vtg) {
  __shared__ float mu_s[64], rs_s[64];
  __shared__ short Vlds[64][264];          // [c_local][v_channel], +8 pad
  const int tid = threadIdx.x;
  const int w = tid >> 6, l = tid & 63;
  const int b = blockIdx.x >> 5;
  const int c0 = (blockIdx.x & 31) * 64;
  const size_t rowbase = (size_t)b * C_ + c0;

  // stats: wave w handles rows w*16..+15, lane reads 12 shorts/row
  for (int rr = w*16; rr < w*16 + 16; ++rr) {
    const short* yr = y1 + (rowbase + rr) * E_ + l * 12;
    float s = 0.f, s2 = 0.f;
    #pragma unroll
    for (int j = 0; j < 3; ++j) {
      short4v v = *(const short4v*)(yr + j*4);
      #pragma unroll
      for (int t = 0; t < 4; ++t) { float f = bf2f(v[t]); s += f; s2 += f*f; }
    }
    #pragma unroll
    for (int off = 1; off < 64; off <<= 1) {
      s  += __shfl_xor(s, off);
      s2 += __shfl_xor(s2, off);
    }
    if (l == 0) {
      float mu = s * (1.f / E_);
      float var = s2 * (1.f / E_) - mu * mu;
      mu_s[rr] = mu;
      rs_s[rr] = rsqrtf(var + 1e-5f);
    }
  }
  __syncthreads();

  // emit Q,K: 4 rows x 64 chunks per iteration
  {
    const int chunk = tid & 63, e0 = chunk * 8;
    float gg[8], ee[8];
    #pragma unroll
    for (int j = 0; j < 8; ++j) { gg[j] = g1[e0+j]; ee[j] = be1[e0+j]; }
    const int isQ = (e0 < 256);
    const int eb  = isQ ? e0 : e0 - 256;
    const int h = eb >> 6, d0 = eb & 63;
    short* dst = (isQ ? Qg : Kg) + ((size_t)(b*H_ + h) * C_ + c0) * D_ + d0;
    const float qs = isQ ? 0.125f : 1.f;
    for (int rg = 0; rg < 16; ++rg) {
      int rr = rg*4 + (tid >> 6);
      short8v v = *(const short8v*)(y1 + (rowbase + rr) * E_ + e0);
      float mu = mu_s[rr], rs = rs_s[rr];
      short8v o;
      #pragma unroll
      for (int j = 0; j < 8; ++j)
        o[j] = f2bf(((bf2f(v[j]) - mu) * rs * gg[j] + ee[j]) * qs);
      *(short8v*)(dst + (size_t)rr * D_) = o;
    }
  }
  // emit V into LDS: 8 rows x 32 chunks per iteration
  {
    const int chunk = tid & 31, e0 = 512 + chunk * 8;
    float gg[8], ee[8];
    #pragma unroll
    for (int j = 0; j < 8; ++j) { gg[j] = g1[e0+j]; ee[j] = be1[e0+j]; }
    for (int rg = 0; rg < 8; ++rg) {
      int rr = rg*8 + (tid >> 5);
      short8v v = *(const short8v*)(y1 + (rowbase + rr) * E_ + e0);
      float mu = mu_s[rr], rs = rs_s[rr];
      short8v o;
      #pragma unroll
      for (int j = 0; j < 8; ++j)
        o[j] = f2bf((bf2f(v[j]) - mu) * rs * gg[j] + ee[j]);
      *(short8v*)&Vlds[rr][chunk * 8] = o;
    }
  }
  __syncthreads();
  // write Vt: thread = (h,d) channel, 64 c's -> coalesced 16B chunks
  {
    const int h = tid >> 6, d = tid & 63;
    short* dst = Vtg + ((size_t)(b*H_ + h) * D_ + d) * C_ + c0;
    #pragma unroll
    for (int c8 = 0; c8 < 8; ++c8) {
      short8v vv;
      #pragma unroll
      for (int j = 0; j < 8; ++j) vv[j] = Vlds[c8*8 + j][tid];
      *(short8v*)(dst + c8*8) = vv;
    }
  }
}

// ---- MFMA flash attention (as R1), epilogue now emits bf16 ob ----
__global__ __launch_bounds__(256, 4) void attn_mfma_kernel(
    const short* __restrict__ Qg, const short* __restrict__ Kg,
    const short* __restrict__ Vtg, short* __restrict__ ob) {
  __shared__ short Ks[64*72];
  __shared__ short Vs[64*72];
  __shared__ short Ps[4][16*72];
  const int tid = threadIdx.x;
  const int w  = tid >> 6;
  const int l  = tid & 63, lo = l & 15, hi = l >> 4;
  const int qt = blockIdx.x, bh = blockIdx.y;
  const size_t hd = (size_t)bh * (C_ * D_);
  const int q0 = qt * 64 + w * 16;

  const short8v bq0 = *(const short8v*)(Qg + hd + (size_t)(q0+lo)*D_ + hi*8);
  const short8v bq1 = *(const short8v*)(Qg + hd + (size_t)(q0+lo)*D_ + 32 + hi*8);

  float mrun = -3.0e38f, lrun = 0.f;
  f32x4 Oacc[4] = {{0,0,0,0},{0,0,0,0},{0,0,0,0},{0,0,0,0}};
  short* Pw = &Ps[w][0];

  for (int kt = 0; kt < 32; ++kt) {
    __syncthreads();
    #pragma unroll
    for (int i = 0; i < 2; ++i) {
      int id = tid + i * 256;
      int row = id >> 3, c8 = (id & 7) * 8;
      *(short8v*)&Ks[row*72 + c8] =
          *(const short8v*)(Kg + hd + (size_t)(kt*64 + row)*D_ + c8);
      *(short8v*)&Vs[row*72 + c8] =
          *(const short8v*)(Vtg + hd + (size_t)row*C_ + kt*64 + c8);
    }
    __syncthreads();

    f32x4 st[4];
    #pragma unroll
    for (int mt = 0; mt < 4; ++mt) {
      short8v ka = *(short8v*)&Ks[(mt*16 + lo)*72 + hi*8];
      short8v kb = *(short8v*)&Ks[(mt*16 + lo)*72 + 32 + hi*8];
      f32x4 z = {0.f, 0.f, 0.f, 0.f};
      z      = __builtin_amdgcn_mfma_f32_16x16x32_bf16(ka, bq0, z, 0, 0, 0);
      st[mt] = __builtin_amdgcn_mfma_f32_16x16x32_bf16(kb, bq1, z, 0, 0, 0);
    }

    float ps[16];
    float tmax = -3.0e38f;
    #pragma unroll
    for (int mt = 0; mt < 4; ++mt)
      #pragma unroll
      for (int r = 0; r < 4; ++r) {
        float v = st[mt][r];
        ps[mt*4 + r] = v;
        tmax = fmaxf(tmax, v);
      }
    tmax = fmaxf(tmax, __shfl_xor(tmax, 16));
    tmax = fmaxf(tmax, __shfl_xor(tmax, 32));
    float mnew = fmaxf(mrun, tmax);
    float corr = __expf(mrun - mnew);
    mrun = mnew;
    float ll = 0.f;
    #pragma unroll
    for (int i = 0; i < 16; ++i) {
      float p = __expf(ps[i] - mnew);
      ps[i] = p;
      ll += p;
    }
    ll += __shfl_xor(ll, 16);
    ll += __shfl_xor(ll, 32);
    lrun = lrun * corr + ll;

    float cc[4];
    #pragma unroll
    for (int r = 0; r < 4; ++r) cc[r] = __shfl(corr, hi*4 + r);
    #pragma unroll
    for (int nt = 0; nt < 4; ++nt)
      #pragma unroll
      for (int r = 0; r < 4; ++r) Oacc[nt][r] *= cc[r];

    #pragma unroll
    for (int mt = 0; mt < 4; ++mt) {
      short4v pk;
      pk[0] = f2bf(ps[mt*4+0]); pk[1] = f2bf(ps[mt*4+1]);
      pk[2] = f2bf(ps[mt*4+2]); pk[3] = f2bf(ps[mt*4+3]);
      *(short4v*)&Pw[lo*72 + mt*16 + hi*4] = pk;
    }
    asm volatile("s_waitcnt lgkmcnt(0)" ::: "memory");

    short8v pa0 = *(short8v*)&Pw[lo*72 + hi*8];
    short8v pa1 = *(short8v*)&Pw[lo*72 + 32 + hi*8];
    #pragma unroll
    for (int nt = 0; nt < 4; ++nt) {
      short8v vb0 = *(short8v*)&Vs[(nt*16 + lo)*72 + hi*8];
      short8v vb1 = *(short8v*)&Vs[(nt*16 + lo)*72 + 32 + hi*8];
      Oacc[nt] = __builtin_amdgcn_mfma_f32_16x16x32_bf16(pa0, vb0, Oacc[nt], 0,0,0);
      Oacc[nt] = __builtin_amdgcn_mfma_f32_16x16x32_bf16(pa1, vb1, Oacc[nt], 0,0,0);
    }
  }

  float linv = 1.f / lrun;
  float li[4];
  #pragma unroll
  for (int r = 0; r < 4; ++r) li[r] = __shfl(linv, hi*4 + r);
  const int b = bh >> 2, h = bh & 3;
  short* obp = ob + ((size_t)b * C_ + q0) * L_ + h * D_;
  #pragma unroll
  for (int nt = 0; nt < 4; ++nt)
    #pragma unroll
    for (int r = 0; r < 4; ++r)
      obp[(hi*4 + r) * L_ + nt*16 + lo] = f2bf(Oacc[nt][r] * li[r]);
}

// ---- GEMM2 + LN2 + residual, fused. BM=64, full N=256 per block ----
__global__ __launch_bounds__(256) void gemm2_ln_mfma_kernel(
    const short* __restrict__ ob, const short* __restrict__ W2t,
    const float* __restrict__ b2, const float* __restrict__ g2,
    const float* __restrict__ be2, const float* __restrict__ x,
    float* __restrict__ out) {
  __shared__ short As[64*72];        // 9 KB
  __shared__ short Bs[256*72];       // 36 KB (W2t rows)
  __shared__ float2 red[2][2][32];
  const int tid = threadIdx.x;
  const int w = tid >> 6, l = tid & 63, lo = l & 15, hi = l >> 4;
  const int wr = w >> 1, wc = w & 1;
  const int m0 = blockIdx.x * 64;

  f32x4 acc[2][8];
  #pragma unroll
  for (int m = 0; m < 2; ++m)
    #pragma unroll
    for (int n = 0; n < 8; ++n) acc[m][n] = (f32x4){0.f,0.f,0.f,0.f};

  for (int kt = 0; kt < 4; ++kt) {
    __syncthreads();
    #pragma unroll
    for (int i = 0; i < 2; ++i) {      // A: 64 rows x 8 chunks = 512
      int id = tid + i * 256;
      int row = id >> 3, k8 = (id & 7) * 8;
      *(short8v*)&As[row*72 + k8] =
          *(const short8v*)(ob + (size_t)(m0 + row) * 256 + kt*64 + k8);
    }
    #pragma unroll
    for (int i = 0; i < 8; ++i) {      // B: 256 rows x 8 chunks = 2048
      int id = tid + i * 256;
      int row = id >> 3, k8 = (id & 7) * 8;
      *(short8v*)&Bs[row*72 + k8] =
          *(const short8v*)(W2t + (size_t)row * 256 + kt*64 + k8);
    }
    __syncthreads();
    #pragma unroll
    for (int kk = 0; kk < 2; ++kk) {
      short8v af[2], bf[8];
      #pragma unroll
      for (int m = 0; m < 2; ++m)
        af[m] = *(short8v*)&As[(wr*32 + m*16 + lo)*72 + kk*32 + hi*8];
      #pragma unroll
      for (int n = 0; n < 8; ++n)
        bf[n] = *(short8v*)&Bs[(wc*128 + n*16 + lo)*72 + kk*32 + hi*8];
      #pragma unroll
      for (int m = 0; m < 2; ++m)
        #pragma unroll
        for (int n = 0; n < 8; ++n)
          acc[m][n] = __builtin_amdgcn_mfma_f32_16x16x32_bf16(af[m], bf[n], acc[m][n], 0,0,0);
    }
  }

  // bias + per-row stats (rows split across the two wc waves)
  float bb[8], gg[8], ee[8];
  #pragma unroll
  for (int n = 0; n < 8; ++n) {
    int col = wc*128 + n*16 + lo;
    bb[n] = b2[col]; gg[n] = g2[col]; ee[n] = be2[col];
  }
  float ps[2][4], pq[2][4];
  #pragma unroll
  for (int m = 0; m < 2; ++m)
    #pragma unroll
    for (int r = 0; r < 4; ++r) {
      float s = 0.f, s2 = 0.f;
      #pragma unroll
      for (int n = 0; n < 8; ++n) {
        float v = acc[m][n][r] + bb[n];
        acc[m][n][r] = v;
        s += v; s2 += v*v;
      }
      ps[m][r] = s; pq[m][r] = s2;
    }
  #pragma unroll
  for (int off = 1; off < 16; off <<= 1)
    #pragma unroll
    for (int m = 0; m < 2; ++m)
      #pragma unroll
      for (int r = 0; r < 4; ++r) {
        ps[m][r] += __shfl_xor(ps[m][r], off);
        pq[m][r] += __shfl_xor(pq[m][r], off);
      }
  if (lo == 0)
    #pragma unroll
    for (int m = 0; m < 2; ++m)
      #pragma unroll
      for (int r = 0; r < 4; ++r)
        red[wr][wc][m*16 + hi*4 + r] = make_float2(ps[m][r], pq[m][r]);
  __syncthreads();

  #pragma unroll
  for (int m = 0; m < 2; ++m)
    #pragma unroll
    for (int r = 0; r < 4; ++r) {
      float2 t0 = red[wr][0][m*16 + hi*4 + r];
      float2 t1 = red[wr][1][m*16 + hi*4 + r];
      float s = t0.x + t1.x, s2 = t0.y + t1.y;
      float mu  = s * (1.f / L_);
      float var = s2 * (1.f / L_) - mu * mu;
      float rs  = rsqrtf(var + 1e-5f);
      const int grow = m0 + wr*32 + m*16 + hi*4 + r;
      const float* xr = x + (size_t)grow * L_ + wc*128;
      float* orow = out + (size_t)grow * L_ + wc*128;
      #pragma unroll
      for (int n = 0; n < 8; ++n)
        orow[n*16 + lo] = (acc[m][n][r] - mu) * rs * gg[n] + ee[n] + xr[n*16 + lo];
    }
}

extern "C" void kernel_launch(void* const* d_in, const int* in_sizes, int n_in,
                              void* d_out, int out_size, void* d_ws, size_t ws_size,
                              hipStream_t stream) {
  const float* x   = (const float*)d_in[0];
  const float* W1  = (const float*)d_in[1];
  const float* b1  = (const float*)d_in[2];
  const float* g1  = (const float*)d_in[3];
  const float* be1 = (const float*)d_in[4];
  const float* W2  = (const float*)d_in[5];
  const float* b2  = (const float*)d_in[6];
  const float* g2  = (const float*)d_in[7];
  const float* be2 = (const float*)d_in[8];
  float* out = (float*)d_out;

  const size_t HDSZ = (size_t)B_ * H_ * C_ * D_;   // 4,194,304
  short* xb  = (short*)d_ws;          // [M][256] bf16
  short* W1t = xb  + (size_t)M_ * L_; // [768][256] bf16
  short* W2t = W1t + (size_t)L_ * E_; // [256][256] bf16
  short* y1  = W2t + (size_t)L_ * L_; // [M][768] bf16
  short* Qg  = y1  + (size_t)M_ * E_; // [bh][c][64]
  short* Kg  = Qg  + HDSZ;
  short* Vtg = Kg  + HDSZ;            // [bh][64][c]
  short* obm = Vtg + HDSZ;            // [M][256] bf16

  cvt_x_kernel<<<(M_ * L_) / (256 * 8), 256, 0, stream>>>(x, xb);
  transpose_w_kernel<<<dim3(8, 24), 256, 0, stream>>>(W1, W1t, L_, E_);
  transpose_w_kernel<<<dim3(8, 8),  256, 0, stream>>>(W2, W2t, L_, L_);
  gemm1_mfma_kernel<<<dim3(M_ / 128, E_ / 128), 256, 0, stream>>>(xb, W1t, b1, y1);
  ln1_kernel<<<M_ / 64, 256, 0, stream>>>(y1, g1, be1, Qg, Kg, Vtg);
  attn_mfma_kernel<<<dim3(32, 32), 256, 0, stream>>>(Qg, Kg, Vtg, obm);
  gemm2_ln_mfma_kernel<<<M_ / 64, 256, 0, stream>>>(obm, W2t, b2, g2, be2, x, out);
}

// Round 4
// 130.815 us; speedup vs baseline: 10.5199x; 1.1052x over previous
//
#include <hip/hip_runtime.h>
#include <hip/hip_bf16.h>

#define B_ 8
#define C_ 2048
#define L_ 256
#define E_ 768
#define H_ 4
#define D_ 64
#define M_ (B_*C_)   // 16384 rows

typedef __attribute__((ext_vector_type(8))) short short8v;   // 8 bf16 (4 VGPR) MFMA A/B frag
typedef __attribute__((ext_vector_type(4))) short short4v;   // 8B packed store
typedef __attribute__((ext_vector_type(4))) float f32x4;     // MFMA C/D frag

__device__ __forceinline__ short f2bf(float f) {             // f32 -> bf16 RNE
  union { float f; unsigned u; } v; v.f = f;
  unsigned r = v.u + 0x7FFFu + ((v.u >> 16) & 1u);
  return (short)(r >> 16);
}
__device__ __forceinline__ float bf2f(short s) {
  union { unsigned u; float f; } v; v.u = ((unsigned)(unsigned short)s) << 16;
  return v.f;
}

// async global->LDS, 16B per lane; LDS dest = uniform base + lane*16 (m104)
__device__ __forceinline__ void gll16(const void* g, void* l) {
  __builtin_amdgcn_global_load_lds(
      (const __attribute__((address_space(1))) unsigned int*)g,
      (__attribute__((address_space(3))) unsigned int*)l, 16, 0, 0);
}

// ---- prep: x f32 -> bf16 (same layout) ----
__global__ __launch_bounds__(256) void cvt_x_kernel(const float* __restrict__ x,
                                                    short* __restrict__ xb) {
  int id = blockIdx.x * 256 + threadIdx.x;
  const float4* src = (const float4*)x + (size_t)id * 2;
  float4 a = src[0], b = src[1];
  short8v p;
  p[0]=f2bf(a.x); p[1]=f2bf(a.y); p[2]=f2bf(a.z); p[3]=f2bf(a.w);
  p[4]=f2bf(b.x); p[5]=f2bf(b.y); p[6]=f2bf(b.z); p[7]=f2bf(b.w);
  *(short8v*)(xb + (size_t)id * 8) = p;
}

// ---- prep: W f32 [K][N] -> Wt bf16 [N][K] via 32x32 LDS tiles ----
__global__ __launch_bounds__(256) void transpose_w_kernel(const float* __restrict__ W,
                                                          short* __restrict__ Wt,
                                                          int K, int N) {
  __shared__ float ld[32][33];
  const int k0 = blockIdx.x * 32, n0 = blockIdx.y * 32;
  const int tx = threadIdx.x & 31, ty = threadIdx.x >> 5;
  #pragma unroll
  for (int j = 0; j < 4; ++j)
    ld[ty + j*8][tx] = W[(size_t)(k0 + ty + j*8) * N + n0 + tx];
  __syncthreads();
  const int r  = threadIdx.x >> 3;
  const int c0 = (threadIdx.x & 7) * 4;
  short4v o;
  o[0]=f2bf(ld[c0+0][r]); o[1]=f2bf(ld[c0+1][r]);
  o[2]=f2bf(ld[c0+2][r]); o[3]=f2bf(ld[c0+3][r]);
  *(short4v*)(Wt + (size_t)(n0 + r) * K + k0 + c0) = o;
}

// ---- GEMM1: y1[M][768] = xb[M][256] @ W1 (+b1), bf16 MFMA, 128x128 tile ----
__global__ __launch_bounds__(256) void gemm1_mfma_kernel(
    const short* __restrict__ xb, const short* __restrict__ W1t,
    const float* __restrict__ b1, short* __restrict__ y1) {
  __shared__ short As[128*72];
  __shared__ short Bs[128*72];
  const int tid = threadIdx.x;
  const int w = tid >> 6, l = tid & 63, lo = l & 15, hi = l >> 4;
  const int wr = w >> 1, wc = w & 1;
  const int m0 = blockIdx.x * 128, n0 = blockIdx.y * 128;

  f32x4 acc[4][4];
  #pragma unroll
  for (int m = 0; m < 4; ++m)
    #pragma unroll
    for (int n = 0; n < 4; ++n) acc[m][n] = (f32x4){0.f,0.f,0.f,0.f};

  for (int kt = 0; kt < 4; ++kt) {
    __syncthreads();
    #pragma unroll
    for (int i = 0; i < 4; ++i) {
      int id = tid + i * 256;
      int row = id >> 3, k8 = (id & 7) * 8;
      *(short8v*)&As[row*72 + k8] =
          *(const short8v*)(xb + (size_t)(m0 + row) * 256 + kt*64 + k8);
      *(short8v*)&Bs[row*72 + k8] =
          *(const short8v*)(W1t + (size_t)(n0 + row) * 256 + kt*64 + k8);
    }
    __syncthreads();
    #pragma unroll
    for (int kk = 0; kk < 2; ++kk) {
      short8v af[4], bf[4];
      #pragma unroll
      for (int m = 0; m < 4; ++m)
        af[m] = *(short8v*)&As[(wr*64 + m*16 + lo)*72 + kk*32 + hi*8];
      #pragma unroll
      for (int n = 0; n < 4; ++n)
        bf[n] = *(short8v*)&Bs[(wc*64 + n*16 + lo)*72 + kk*32 + hi*8];
      #pragma unroll
      for (int m = 0; m < 4; ++m)
        #pragma unroll
        for (int n = 0; n < 4; ++n)
          acc[m][n] = __builtin_amdgcn_mfma_f32_16x16x32_bf16(af[m], bf[n], acc[m][n], 0,0,0);
    }
  }

  float bb[4];
  #pragma unroll
  for (int n = 0; n < 4; ++n) bb[n] = b1[n0 + wc*64 + n*16 + lo];
  #pragma unroll
  for (int m = 0; m < 4; ++m) {
    const int gr = m0 + wr*64 + m*16 + hi*4;
    #pragma unroll
    for (int r = 0; r < 4; ++r) {
      short* yp = y1 + (size_t)(gr + r) * E_ + n0 + wc*64;
      #pragma unroll
      for (int n = 0; n < 4; ++n)
        yp[n*16 + lo] = f2bf(acc[m][n][r] + bb[n]);
    }
  }
}

// ---- LN1: y1 -> Q (x0.125, linear), K + Vt PRE-SWIZZLED for attn staging ----
// Swizzle: within each 64-seq tile window, 16B chunk index ^= (row&7), where
// row = seq_local for K, d for Vt. Matches attn's ds_read swizzle (both-sides rule).
__global__ __launch_bounds__(256) void ln1_kernel(
    const short* __restrict__ y1, const float* __restrict__ g1,
    const float* __restrict__ be1,
    short* __restrict__ Qg, short* __restrict__ Kg, short* __restrict__ Vtg) {
  __shared__ float mu_s[64], rs_s[64];
  __shared__ short Vlds[64][264];
  const int tid = threadIdx.x;
  const int w = tid >> 6, l = tid & 63;
  const int b = blockIdx.x >> 5;
  const int c0 = (blockIdx.x & 31) * 64;
  const size_t rowbase = (size_t)b * C_ + c0;

  for (int rr = w*16; rr < w*16 + 16; ++rr) {
    const short* yr = y1 + (rowbase + rr) * E_ + l * 12;
    float s = 0.f, s2 = 0.f;
    #pragma unroll
    for (int j = 0; j < 3; ++j) {
      short4v v = *(const short4v*)(yr + j*4);
      #pragma unroll
      for (int t = 0; t < 4; ++t) { float f = bf2f(v[t]); s += f; s2 += f*f; }
    }
    #pragma unroll
    for (int off = 1; off < 64; off <<= 1) {
      s  += __shfl_xor(s, off);
      s2 += __shfl_xor(s2, off);
    }
    if (l == 0) {
      float mu = s * (1.f / E_);
      float var = s2 * (1.f / E_) - mu * mu;
      mu_s[rr] = mu;
      rs_s[rr] = rsqrtf(var + 1e-5f);
    }
  }
  __syncthreads();

  // emit Q (linear) and K (swizzled): 4 rows x 64 chunks per iteration
  {
    const int chunk = tid & 63, e0 = chunk * 8;
    float gg[8], ee[8];
    #pragma unroll
    for (int j = 0; j < 8; ++j) { gg[j] = g1[e0+j]; ee[j] = be1[e0+j]; }
    const int isQ = (e0 < 256);
    const int eb  = isQ ? e0 : e0 - 256;
    const int h = eb >> 6, d0 = eb & 63;
    short* dstQ = Qg + ((size_t)(b*H_ + h) * C_ + c0) * D_ + d0;
    short* dstK = Kg + ((size_t)(b*H_ + h) * C_ + c0) * D_;
    const float qs = isQ ? 0.125f : 1.f;
    for (int rg = 0; rg < 16; ++rg) {
      int rr = rg*4 + (tid >> 6);
      short8v v = *(const short8v*)(y1 + (rowbase + rr) * E_ + e0);
      float mu = mu_s[rr], rs = rs_s[rr];
      short8v o;
      #pragma unroll
      for (int j = 0; j < 8; ++j)
        o[j] = f2bf(((bf2f(v[j]) - mu) * rs * gg[j] + ee[j]) * qs);
      if (isQ) *(short8v*)(dstQ + (size_t)rr * D_) = o;
      else     *(short8v*)(dstK + (size_t)rr * D_ + ((((d0>>3) ^ (rr&7)) << 3))) = o;
    }
  }
  // emit V into LDS
  {
    const int chunk = tid & 31, e0 = 512 + chunk * 8;
    float gg[8], ee[8];
    #pragma unroll
    for (int j = 0; j < 8; ++j) { gg[j] = g1[e0+j]; ee[j] = be1[e0+j]; }
    for (int rg = 0; rg < 8; ++rg) {
      int rr = rg*8 + (tid >> 5);
      short8v v = *(const short8v*)(y1 + (rowbase + rr) * E_ + e0);
      float mu = mu_s[rr], rs = rs_s[rr];
      short8v o;
      #pragma unroll
      for (int j = 0; j < 8; ++j)
        o[j] = f2bf((bf2f(v[j]) - mu) * rs * gg[j] + ee[j]);
      *(short8v*)&Vlds[rr][chunk * 8] = o;
    }
  }
  __syncthreads();
  // write Vt swizzled: row = d, chunk c8 -> c8 ^ (d&7) within this 64-c window
  {
    const int h = tid >> 6, d = tid & 63;
    short* dst = Vtg + ((size_t)(b*H_ + h) * D_ + d) * C_ + c0;
    #pragma unroll
    for (int c8 = 0; c8 < 8; ++c8) {
      short8v vv;
      #pragma unroll
      for (int j = 0; j < 8; ++j) vv[j] = Vlds[c8*8 + j][tid];
      *(short8v*)(dst + ((c8 ^ (d&7)) << 3)) = vv;
    }
  }
}

// ---- MFMA flash attention: global_load_lds staging, dbuf + vmcnt(4),
//      XOR-swizzled LDS (pre-swizzled in global), defer-max, setprio ----
__global__ __launch_bounds__(256, 4) void attn_mfma_kernel(
    const short* __restrict__ Qg, const short* __restrict__ Kg,
    const short* __restrict__ Vtg, short* __restrict__ ob) {
  __shared__ short Ks[2][4096];     // [buf][64 rows x 64], 128B rows, swizzled image
  __shared__ short Vs[2][4096];     // [buf][64 d-rows x 64 keys]
  __shared__ short Ps[4][1024];     // per-wave P tile [16 q][64 keys], swizzled
  const int tid = threadIdx.x;
  const int w  = tid >> 6;
  const int l  = tid & 63, lo = l & 15, hi = l >> 4;
  const int sw = lo & 7;            // read-side swizzle key (row&7 == lo&7 at all sites)
  const int qt = blockIdx.x, bh = blockIdx.y;
  const size_t hd = (size_t)bh * (C_ * D_);
  const int q0 = qt * 64 + w * 16;

  const short8v bq0 = *(const short8v*)(Qg + hd + (size_t)(q0+lo)*D_ + hi*8);
  const short8v bq1 = *(const short8v*)(Qg + hd + (size_t)(q0+lo)*D_ + 32 + hi*8);

  // staging geometry: wave w DMAs segments {2w, 2w+1} (1KB each) of K and V
  const int segA = w*2, segB = segA + 1;
  const short* Ktile = Kg + hd;                       // + kt*4096 per tile (linear copy)
  const short* Vrow  = Vtg + hd;                      // rows d (C_ elems), + kt*64 per tile
  const int kOffA = segA*512 + l*8, kOffB = segB*512 + l*8;
  const size_t vOffA = (size_t)(segA*8 + (l>>3)) * C_ + (l&7)*8;
  const size_t vOffB = (size_t)(segB*8 + (l>>3)) * C_ + (l&7)*8;

  float mrun = -3.0e38f, lrun = 0.f;
  f32x4 Oacc[4] = {{0,0,0,0},{0,0,0,0},{0,0,0,0},{0,0,0,0}};
  short* Pw = &Ps[w][0];

  // prologue: stage kt=0 -> buf 0
  gll16(Ktile + kOffA, &Ks[0][segA*512]);
  gll16(Ktile + kOffB, &Ks[0][segB*512]);
  gll16(Vrow + vOffA,  &Vs[0][segA*512]);
  gll16(Vrow + vOffB,  &Vs[0][segB*512]);

  int cur = 0;
  for (int kt = 0; kt < 32; ++kt) {
    __builtin_amdgcn_s_barrier();           // all waves done reading buf[cur^1]
    if (kt != 31) {                          // stage kt+1 -> buf[cur^1]
      const short* kn = Ktile + (size_t)(kt+1) * 4096;
      const short* vn = Vrow  + (size_t)(kt+1) * 64;
      gll16(kn + kOffA, &Ks[cur^1][segA*512]);
      gll16(kn + kOffB, &Ks[cur^1][segB*512]);
      gll16(vn + vOffA, &Vs[cur^1][segA*512]);
      gll16(vn + vOffB, &Vs[cur^1][segB*512]);
      asm volatile("s_waitcnt vmcnt(4)" ::: "memory");   // kt's loads landed; kt+1 in flight
    } else {
      asm volatile("s_waitcnt vmcnt(0)" ::: "memory");
    }
    __builtin_amdgcn_s_barrier();           // buf[cur] ready for everyone
    const short* Kc = &Ks[cur][0];
    const short* Vc = &Vs[cur][0];

    // S^T tiles: D[key_local][q]
    f32x4 st[4];
    __builtin_amdgcn_s_setprio(1);
    #pragma unroll
    for (int mt = 0; mt < 4; ++mt) {
      short8v ka = *(const short8v*)&Kc[(mt*16 + lo)*64 + ((hi ^ sw) << 3)];
      short8v kb = *(const short8v*)&Kc[(mt*16 + lo)*64 + (((4 + hi) ^ sw) << 3)];
      f32x4 z = {0.f, 0.f, 0.f, 0.f};
      z      = __builtin_amdgcn_mfma_f32_16x16x32_bf16(ka, bq0, z, 0, 0, 0);
      st[mt] = __builtin_amdgcn_mfma_f32_16x16x32_bf16(kb, bq1, z, 0, 0, 0);
    }
    __builtin_amdgcn_s_setprio(0);

    // online softmax with defer-max (THR=8): lane owns q=lo, 16 of 64 keys
    float ps[16];
    float tmax = -3.0e38f;
    #pragma unroll
    for (int mt = 0; mt < 4; ++mt)
      #pragma unroll
      for (int r = 0; r < 4; ++r) {
        float v = st[mt][r];
        ps[mt*4 + r] = v;
        tmax = fmaxf(tmax, v);
      }
    tmax = fmaxf(tmax, __shfl_xor(tmax, 16));
    tmax = fmaxf(tmax, __shfl_xor(tmax, 32));
    if (__any(tmax > mrun + 8.f)) {          // rescale only on real max growth
      float mnew = fmaxf(mrun, tmax);
      float corr = __expf(mrun - mnew);
      mrun = mnew;
      lrun *= corr;
      float cc[4];
      #pragma unroll
      for (int r = 0; r < 4; ++r) cc[r] = __shfl(corr, hi*4 + r);
      #pragma unroll
      for (int nt = 0; nt < 4; ++nt)
        #pragma unroll
        for (int r = 0; r < 4; ++r) Oacc[nt][r] *= cc[r];
    }
    float ll = 0.f;
    #pragma unroll
    for (int i = 0; i < 16; ++i) {
      float p = __expf(ps[i] - mrun);        // bounded by e^8 when deferred
      ps[i] = p;
      ll += p;
    }
    ll += __shfl_xor(ll, 16);
    ll += __shfl_xor(ll, 32);
    lrun += ll;

    // P (bf16) -> per-wave swizzled LDS [q][key]
    #pragma unroll
    for (int mt = 0; mt < 4; ++mt) {
      short4v pk;
      pk[0] = f2bf(ps[mt*4+0]); pk[1] = f2bf(ps[mt*4+1]);
      pk[2] = f2bf(ps[mt*4+2]); pk[3] = f2bf(ps[mt*4+3]);
      *(short4v*)&Pw[lo*64 + ((((mt<<1) + (hi>>1)) ^ sw) << 3) + ((hi&1) << 2)] = pk;
    }
    asm volatile("s_waitcnt lgkmcnt(0)" ::: "memory");   // same-wave P RAW

    short8v pa0 = *(short8v*)&Pw[lo*64 + ((hi ^ sw) << 3)];
    short8v pa1 = *(short8v*)&Pw[lo*64 + (((4 + hi) ^ sw) << 3)];
    __builtin_amdgcn_s_setprio(1);
    #pragma unroll
    for (int nt = 0; nt < 4; ++nt) {
      short8v vb0 = *(const short8v*)&Vc[(nt*16 + lo)*64 + ((hi ^ sw) << 3)];
      short8v vb1 = *(const short8v*)&Vc[(nt*16 + lo)*64 + (((4 + hi) ^ sw) << 3)];
      Oacc[nt] = __builtin_amdgcn_mfma_f32_16x16x32_bf16(pa0, vb0, Oacc[nt], 0,0,0);
      Oacc[nt] = __builtin_amdgcn_mfma_f32_16x16x32_bf16(pa1, vb1, Oacc[nt], 0,0,0);
    }
    __builtin_amdgcn_s_setprio(0);
    cur ^= 1;
  }

  float linv = 1.f / lrun;
  float li[4];
  #pragma unroll
  for (int r = 0; r < 4; ++r) li[r] = __shfl(linv, hi*4 + r);
  const int b = bh >> 2, h = bh & 3;
  short* obp = ob + ((size_t)b * C_ + q0) * L_ + h * D_;
  #pragma unroll
  for (int nt = 0; nt < 4; ++nt)
    #pragma unroll
    for (int r = 0; r < 4; ++r)
      obp[(hi*4 + r) * L_ + nt*16 + lo] = f2bf(Oacc[nt][r] * li[r]);
}

// ---- GEMM2 + LN2 + residual, fused. BM=64, full N=256 per block ----
__global__ __launch_bounds__(256) void gemm2_ln_mfma_kernel(
    const short* __restrict__ ob, const short* __restrict__ W2t,
    const float* __restrict__ b2, const float* __restrict__ g2,
    const float* __restrict__ be2, const float* __restrict__ x,
    float* __restrict__ out) {
  __shared__ short As[64*72];
  __shared__ short Bs[256*72];
  __shared__ float2 red[2][2][32];
  const int tid = threadIdx.x;
  const int w = tid >> 6, l = tid & 63, lo = l & 15, hi = l >> 4;
  const int wr = w >> 1, wc = w & 1;
  const int m0 = blockIdx.x * 64;

  f32x4 acc[2][8];
  #pragma unroll
  for (int m = 0; m < 2; ++m)
    #pragma unroll
    for (int n = 0; n < 8; ++n) acc[m][n] = (f32x4){0.f,0.f,0.f,0.f};

  for (int kt = 0; kt < 4; ++kt) {
    __syncthreads();
    #pragma unroll
    for (int i = 0; i < 2; ++i) {
      int id = tid + i * 256;
      int row = id >> 3, k8 = (id & 7) * 8;
      *(short8v*)&As[row*72 + k8] =
          *(const short8v*)(ob + (size_t)(m0 + row) * 256 + kt*64 + k8);
    }
    #pragma unroll
    for (int i = 0; i < 8; ++i) {
      int id = tid + i * 256;
      int row = id >> 3, k8 = (id & 7) * 8;
      *(short8v*)&Bs[row*72 + k8] =
          *(const short8v*)(W2t + (size_t)row * 256 + kt*64 + k8);
    }
    __syncthreads();
    #pragma unroll
    for (int kk = 0; kk < 2; ++kk) {
      short8v af[2], bf[8];
      #pragma unroll
      for (int m = 0; m < 2; ++m)
        af[m] = *(short8v*)&As[(wr*32 + m*16 + lo)*72 + kk*32 + hi*8];
      #pragma unroll
      for (int n = 0; n < 8; ++n)
        bf[n] = *(short8v*)&Bs[(wc*128 + n*16 + lo)*72 + kk*32 + hi*8];
      #pragma unroll
      for (int m = 0; m < 2; ++m)
        #pragma unroll
        for (int n = 0; n < 8; ++n)
          acc[m][n] = __builtin_amdgcn_mfma_f32_16x16x32_bf16(af[m], bf[n], acc[m][n], 0,0,0);
    }
  }

  float bb[8], gg[8], ee[8];
  #pragma unroll
  for (int n = 0; n < 8; ++n) {
    int col = wc*128 + n*16 + lo;
    bb[n] = b2[col]; gg[n] = g2[col]; ee[n] = be2[col];
  }
  float ps[2][4], pq[2][4];
  #pragma unroll
  for (int m = 0; m < 2; ++m)
    #pragma unroll
    for (int r = 0; r < 4; ++r) {
      float s = 0.f, s2 = 0.f;
      #pragma unroll
      for (int n = 0; n < 8; ++n) {
        float v = acc[m][n][r] + bb[n];
        acc[m][n][r] = v;
        s += v; s2 += v*v;
      }
      ps[m][r] = s; pq[m][r] = s2;
    }
  #pragma unroll
  for (int off = 1; off < 16; off <<= 1)
    #pragma unroll
    for (int m = 0; m < 2; ++m)
      #pragma unroll
      for (int r = 0; r < 4; ++r) {
        ps[m][r] += __shfl_xor(ps[m][r], off);
        pq[m][r] += __shfl_xor(pq[m][r], off);
      }
  if (lo == 0)
    #pragma unroll
    for (int m = 0; m < 2; ++m)
      #pragma unroll
      for (int r = 0; r < 4; ++r)
        red[wr][wc][m*16 + hi*4 + r] = make_float2(ps[m][r], pq[m][r]);
  __syncthreads();

  #pragma unroll
  for (int m = 0; m < 2; ++m)
    #pragma unroll
    for (int r = 0; r < 4; ++r) {
      float2 t0 = red[wr][0][m*16 + hi*4 + r];
      float2 t1 = red[wr][1][m*16 + hi*4 + r];
      float s = t0.x + t1.x, s2 = t0.y + t1.y;
      float mu  = s * (1.f / L_);
      float var = s2 * (1.f / L_) - mu * mu;
      float rs  = rsqrtf(var + 1e-5f);
      const int grow = m0 + wr*32 + m*16 + hi*4 + r;
      const float* xr = x + (size_t)grow * L_ + wc*128;
      float* orow = out + (size_t)grow * L_ + wc*128;
      #pragma unroll
      for (int n = 0; n < 8; ++n)
        orow[n*16 + lo] = (acc[m][n][r] - mu) * rs * gg[n] + ee[n] + xr[n*16 + lo];
    }
}

extern "C" void kernel_launch(void* const* d_in, const int* in_sizes, int n_in,
                              void* d_out, int out_size, void* d_ws, size_t ws_size,
                              hipStream_t stream) {
  const float* x   = (const float*)d_in[0];
  const float* W1  = (const float*)d_in[1];
  const float* b1  = (const float*)d_in[2];
  const float* g1  = (const float*)d_in[3];
  const float* be1 = (const float*)d_in[4];
  const float* W2  = (const float*)d_in[5];
  const float* b2  = (const float*)d_in[6];
  const float* g2  = (const float*)d_in[7];
  const float* be2 = (const float*)d_in[8];
  float* out = (float*)d_out;

  const size_t HDSZ = (size_t)B_ * H_ * C_ * D_;   // 4,194,304
  short* xb  = (short*)d_ws;          // [M][256] bf16
  short* W1t = xb  + (size_t)M_ * L_; // [768][256] bf16
  short* W2t = W1t + (size_t)L_ * E_; // [256][256] bf16
  short* y1  = W2t + (size_t)L_ * L_; // [M][768] bf16
  short* Qg  = y1  + (size_t)M_ * E_; // [bh][c][64] (pre-scaled)
  short* Kg  = Qg  + HDSZ;            // [bh][c][64] swizzled
  short* Vtg = Kg  + HDSZ;            // [bh][64][c] swizzled
  short* obm = Vtg + HDSZ;            // [M][256] bf16

  cvt_x_kernel<<<(M_ * L_) / (256 * 8), 256, 0, stream>>>(x, xb);
  transpose_w_kernel<<<dim3(8, 24), 256, 0, stream>>>(W1, W1t, L_, E_);
  transpose_w_kernel<<<dim3(8, 8),  256, 0, stream>>>(W2, W2t, L_, L_);
  gemm1_mfma_kernel<<<dim3(M_ / 128, E_ / 128), 256, 0, stream>>>(xb, W1t, b1, y1);
  ln1_kernel<<<M_ / 64, 256, 0, stream>>>(y1, g1, be1, Qg, Kg, Vtg);
  attn_mfma_kernel<<<dim3(32, 32), 256, 0, stream>>>(Qg, Kg, Vtg, obm);
  gemm2_ln_mfma_kernel<<<M_ / 64, 256, 0, stream>>>(obm, W2t, b2, g2, be2, x, out);
}

// Round 5
// 123.512 us; speedup vs baseline: 11.1420x; 1.0591x over previous
//
#include <hip/hip_runtime.h>
#include <hip/hip_bf16.h>

#define B_ 8
#define C_ 2048
#define L_ 256
#define E_ 768
#define H_ 4
#define D_ 64
#define M_ (B_*C_)   // 16384 rows

typedef __attribute__((ext_vector_type(8))) short short8v;   // 8 bf16 (4 VGPR) MFMA A/B frag
typedef __attribute__((ext_vector_type(4))) short short4v;   // 8B packed store
typedef __attribute__((ext_vector_type(4))) float f32x4;     // MFMA C/D frag

__device__ __forceinline__ short f2bf(float f) {             // f32 -> bf16 RNE
  union { float f; unsigned u; } v; v.f = f;
  unsigned r = v.u + 0x7FFFu + ((v.u >> 16) & 1u);
  return (short)(r >> 16);
}
__device__ __forceinline__ float bf2f(short s) {
  union { unsigned u; float f; } v; v.u = ((unsigned)(unsigned short)s) << 16;
  return v.f;
}
// two f32 -> packed bf16x2 in one VALU op (gfx950; no builtin, m240)
__device__ __forceinline__ unsigned cvtpk(float a, float b) {
  unsigned r;
  asm("v_cvt_pk_bf16_f32 %0, %1, %2" : "=v"(r) : "v"(a), "v"(b));
  return r;
}
__device__ __forceinline__ float exp2x(float x) {            // 2^x, single v_exp_f32
  float r;
  asm("v_exp_f32 %0, %1" : "=v"(r) : "v"(x));
  return r;
}

// async global->LDS, 16B per lane; LDS dest = uniform base + lane*16 (m104)
__device__ __forceinline__ void gll16(const void* g, void* l) {
  __builtin_amdgcn_global_load_lds(
      (const __attribute__((address_space(1))) unsigned int*)g,
      (__attribute__((address_space(3))) unsigned int*)l, 16, 0, 0);
}

// ---- prep: W f32 [K][N] -> Wt bf16 [N][K] via 32x32 LDS tiles ----
__global__ __launch_bounds__(256) void transpose_w_kernel(const float* __restrict__ W,
                                                          short* __restrict__ Wt,
                                                          int K, int N) {
  __shared__ float ld[32][33];
  const int k0 = blockIdx.x * 32, n0 = blockIdx.y * 32;
  const int tx = threadIdx.x & 31, ty = threadIdx.x >> 5;
  #pragma unroll
  for (int j = 0; j < 4; ++j)
    ld[ty + j*8][tx] = W[(size_t)(k0 + ty + j*8) * N + n0 + tx];
  __syncthreads();
  const int r  = threadIdx.x >> 3;
  const int c0 = (threadIdx.x & 7) * 4;
  short4v o;
  o[0]=f2bf(ld[c0+0][r]); o[1]=f2bf(ld[c0+1][r]);
  o[2]=f2bf(ld[c0+2][r]); o[3]=f2bf(ld[c0+3][r]);
  *(short4v*)(Wt + (size_t)(n0 + r) * K + k0 + c0) = o;
}

// ---- GEMM1: y1[M][768] = x[M][256] @ W1 (+b1); x converted in staging ----
__global__ __launch_bounds__(256) void gemm1_mfma_kernel(
    const float* __restrict__ x, const short* __restrict__ W1t,
    const float* __restrict__ b1, short* __restrict__ y1) {
  __shared__ short As[128*72];
  __shared__ short Bs[128*72];
  const int tid = threadIdx.x;
  const int w = tid >> 6, l = tid & 63, lo = l & 15, hi = l >> 4;
  const int wr = w >> 1, wc = w & 1;
  const int m0 = blockIdx.x * 128, n0 = blockIdx.y * 128;

  f32x4 acc[4][4];
  #pragma unroll
  for (int m = 0; m < 4; ++m)
    #pragma unroll
    for (int n = 0; n < 4; ++n) acc[m][n] = (f32x4){0.f,0.f,0.f,0.f};

  for (int kt = 0; kt < 4; ++kt) {
    __syncthreads();
    #pragma unroll
    for (int i = 0; i < 4; ++i) {
      int id = tid + i * 256;
      int row = id >> 3, k8 = (id & 7) * 8;
      const float* ap = x + (size_t)(m0 + row) * 256 + kt*64 + k8;
      float4 a0 = ((const float4*)ap)[0], a1 = ((const float4*)ap)[1];
      uint4 pk;
      pk.x = cvtpk(a0.x, a0.y); pk.y = cvtpk(a0.z, a0.w);
      pk.z = cvtpk(a1.x, a1.y); pk.w = cvtpk(a1.z, a1.w);
      *(uint4*)&As[row*72 + k8] = pk;
      *(short8v*)&Bs[row*72 + k8] =
          *(const short8v*)(W1t + (size_t)(n0 + row) * 256 + kt*64 + k8);
    }
    __syncthreads();
    #pragma unroll
    for (int kk = 0; kk < 2; ++kk) {
      short8v af[4], bf[4];
      #pragma unroll
      for (int m = 0; m < 4; ++m)
        af[m] = *(short8v*)&As[(wr*64 + m*16 + lo)*72 + kk*32 + hi*8];
      #pragma unroll
      for (int n = 0; n < 4; ++n)
        bf[n] = *(short8v*)&Bs[(wc*64 + n*16 + lo)*72 + kk*32 + hi*8];
      #pragma unroll
      for (int m = 0; m < 4; ++m)
        #pragma unroll
        for (int n = 0; n < 4; ++n)
          acc[m][n] = __builtin_amdgcn_mfma_f32_16x16x32_bf16(af[m], bf[n], acc[m][n], 0,0,0);
    }
  }

  float bb[4];
  #pragma unroll
  for (int n = 0; n < 4; ++n) bb[n] = b1[n0 + wc*64 + n*16 + lo];
  #pragma unroll
  for (int m = 0; m < 4; ++m) {
    const int gr = m0 + wr*64 + m*16 + hi*4;
    #pragma unroll
    for (int r = 0; r < 4; ++r) {
      short* yp = y1 + (size_t)(gr + r) * E_ + n0 + wc*64;
      #pragma unroll
      for (int n = 0; n < 4; ++n)
        yp[n*16 + lo] = f2bf(acc[m][n][r] + bb[n]);
    }
  }
}

// ---- LN1: y1 -> Q (x 0.125*log2e, linear), K + Vt PRE-SWIZZLED for attn ----
__global__ __launch_bounds__(256) void ln1_kernel(
    const short* __restrict__ y1, const float* __restrict__ g1,
    const float* __restrict__ be1,
    short* __restrict__ Qg, short* __restrict__ Kg, short* __restrict__ Vtg) {
  __shared__ float mu_s[64], rs_s[64];
  __shared__ short Vlds[64][264];
  const int tid = threadIdx.x;
  const int w = tid >> 6, l = tid & 63;
  const int b = blockIdx.x >> 5;
  const int c0 = (blockIdx.x & 31) * 64;
  const size_t rowbase = (size_t)b * C_ + c0;

  for (int rr = w*16; rr < w*16 + 16; ++rr) {
    const short* yr = y1 + (rowbase + rr) * E_ + l * 12;
    float s = 0.f, s2 = 0.f;
    #pragma unroll
    for (int j = 0; j < 3; ++j) {
      short4v v = *(const short4v*)(yr + j*4);
      #pragma unroll
      for (int t = 0; t < 4; ++t) { float f = bf2f(v[t]); s += f; s2 += f*f; }
    }
    #pragma unroll
    for (int off = 1; off < 64; off <<= 1) {
      s  += __shfl_xor(s, off);
      s2 += __shfl_xor(s2, off);
    }
    if (l == 0) {
      float mu = s * (1.f / E_);
      float var = s2 * (1.f / E_) - mu * mu;
      mu_s[rr] = mu;
      rs_s[rr] = rsqrtf(var + 1e-5f);
    }
  }
  __syncthreads();

  // emit Q (linear, log2-domain scale) and K (swizzled)
  {
    const int chunk = tid & 63, e0 = chunk * 8;
    float gg[8], ee[8];
    #pragma unroll
    for (int j = 0; j < 8; ++j) { gg[j] = g1[e0+j]; ee[j] = be1[e0+j]; }
    const int isQ = (e0 < 256);
    const int eb  = isQ ? e0 : e0 - 256;
    const int h = eb >> 6, d0 = eb & 63;
    short* dstQ = Qg + ((size_t)(b*H_ + h) * C_ + c0) * D_ + d0;
    short* dstK = Kg + ((size_t)(b*H_ + h) * C_ + c0) * D_;
    const float qs = isQ ? 0.18033688011f : 1.f;   // 0.125 * log2(e)
    for (int rg = 0; rg < 16; ++rg) {
      int rr = rg*4 + (tid >> 6);
      short8v v = *(const short8v*)(y1 + (rowbase + rr) * E_ + e0);
      float mu = mu_s[rr], rs = rs_s[rr];
      short8v o;
      #pragma unroll
      for (int j = 0; j < 8; ++j)
        o[j] = f2bf(((bf2f(v[j]) - mu) * rs * gg[j] + ee[j]) * qs);
      if (isQ) *(short8v*)(dstQ + (size_t)rr * D_) = o;
      else     *(short8v*)(dstK + (size_t)rr * D_ + ((((d0>>3) ^ (rr&7)) << 3))) = o;
    }
  }
  // emit V into LDS
  {
    const int chunk = tid & 31, e0 = 512 + chunk * 8;
    float gg[8], ee[8];
    #pragma unroll
    for (int j = 0; j < 8; ++j) { gg[j] = g1[e0+j]; ee[j] = be1[e0+j]; }
    for (int rg = 0; rg < 8; ++rg) {
      int rr = rg*8 + (tid >> 5);
      short8v v = *(const short8v*)(y1 + (rowbase + rr) * E_ + e0);
      float mu = mu_s[rr], rs = rs_s[rr];
      short8v o;
      #pragma unroll
      for (int j = 0; j < 8; ++j)
        o[j] = f2bf((bf2f(v[j]) - mu) * rs * gg[j] + ee[j]);
      *(short8v*)&Vlds[rr][chunk * 8] = o;
    }
  }
  __syncthreads();
  // write Vt swizzled: row = d, chunk c8 -> c8 ^ (d&7) within this 64-c window
  {
    const int h = tid >> 6, d = tid & 63;
    short* dst = Vtg + ((size_t)(b*H_ + h) * D_ + d) * C_ + c0;
    #pragma unroll
    for (int c8 = 0; c8 < 8; ++c8) {
      short8v vv;
      #pragma unroll
      for (int j = 0; j < 8; ++j) vv[j] = Vlds[c8*8 + j][tid];
      *(short8v*)(dst + ((c8 ^ (d&7)) << 3)) = vv;
    }
  }
}

// ---- MFMA flash attention: gll staging + dbuf + vmcnt(4), swizzled LDS,
//      log2-domain softmax, cvt_pk P-pack, defer-max, setprio ----
__global__ __launch_bounds__(256, 4) void attn_mfma_kernel(
    const short* __restrict__ Qg, const short* __restrict__ Kg,
    const short* __restrict__ Vtg, short* __restrict__ ob) {
  __shared__ short Ks[2][4096];
  __shared__ short Vs[2][4096];
  __shared__ short Ps[4][1024];
  const int tid = threadIdx.x;
  const int w  = tid >> 6;
  const int l  = tid & 63, lo = l & 15, hi = l >> 4;
  const int sw = lo & 7;
  const int qt = blockIdx.x, bh = blockIdx.y;
  const size_t hd = (size_t)bh * (C_ * D_);
  const int q0 = qt * 64 + w * 16;

  const short8v bq0 = *(const short8v*)(Qg + hd + (size_t)(q0+lo)*D_ + hi*8);
  const short8v bq1 = *(const short8v*)(Qg + hd + (size_t)(q0+lo)*D_ + 32 + hi*8);

  const int segA = w*2, segB = segA + 1;
  const short* Ktile = Kg + hd;
  const short* Vrow  = Vtg + hd;
  const int kOffA = segA*512 + l*8, kOffB = segB*512 + l*8;
  const size_t vOffA = (size_t)(segA*8 + (l>>3)) * C_ + (l&7)*8;
  const size_t vOffB = (size_t)(segB*8 + (l>>3)) * C_ + (l&7)*8;

  float mrun = -3.0e38f, lrun = 0.f;     // log2-domain running max
  f32x4 Oacc[4] = {{0,0,0,0},{0,0,0,0},{0,0,0,0},{0,0,0,0}};
  short* Pw = &Ps[w][0];

  gll16(Ktile + kOffA, &Ks[0][segA*512]);
  gll16(Ktile + kOffB, &Ks[0][segB*512]);
  gll16(Vrow + vOffA,  &Vs[0][segA*512]);
  gll16(Vrow + vOffB,  &Vs[0][segB*512]);

  int cur = 0;
  for (int kt = 0; kt < 32; ++kt) {
    __builtin_amdgcn_s_barrier();
    if (kt != 31) {
      const short* kn = Ktile + (size_t)(kt+1) * 4096;
      const short* vn = Vrow  + (size_t)(kt+1) * 64;
      gll16(kn + kOffA, &Ks[cur^1][segA*512]);
      gll16(kn + kOffB, &Ks[cur^1][segB*512]);
      gll16(vn + vOffA, &Vs[cur^1][segA*512]);
      gll16(vn + vOffB, &Vs[cur^1][segB*512]);
      asm volatile("s_waitcnt vmcnt(4)" ::: "memory");
    } else {
      asm volatile("s_waitcnt vmcnt(0)" ::: "memory");
    }
    __builtin_amdgcn_s_barrier();
    const short* Kc = &Ks[cur][0];
    const short* Vc = &Vs[cur][0];

    f32x4 st[4];
    __builtin_amdgcn_s_setprio(1);
    #pragma unroll
    for (int mt = 0; mt < 4; ++mt) {
      short8v ka = *(const short8v*)&Kc[(mt*16 + lo)*64 + ((hi ^ sw) << 3)];
      short8v kb = *(const short8v*)&Kc[(mt*16 + lo)*64 + (((4 + hi) ^ sw) << 3)];
      f32x4 z = {0.f, 0.f, 0.f, 0.f};
      z      = __builtin_amdgcn_mfma_f32_16x16x32_bf16(ka, bq0, z, 0, 0, 0);
      st[mt] = __builtin_amdgcn_mfma_f32_16x16x32_bf16(kb, bq1, z, 0, 0, 0);
    }
    __builtin_amdgcn_s_setprio(0);

    // online softmax, log2 domain; defer threshold 8*log2(e)
    float ps[16];
    float tmax = -3.0e38f;
    #pragma unroll
    for (int mt = 0; mt < 4; ++mt)
      #pragma unroll
      for (int r = 0; r < 4; ++r) {
        float v = st[mt][r];
        ps[mt*4 + r] = v;
        tmax = fmaxf(tmax, v);
      }
    tmax = fmaxf(tmax, __shfl_xor(tmax, 16));
    tmax = fmaxf(tmax, __shfl_xor(tmax, 32));
    if (__any(tmax > mrun + 11.5415603f)) {
      float mnew = fmaxf(mrun, tmax);
      float corr = exp2x(mrun - mnew);
      mrun = mnew;
      lrun *= corr;
      float cc[4];
      #pragma unroll
      for (int r = 0; r < 4; ++r) cc[r] = __shfl(corr, hi*4 + r);
      #pragma unroll
      for (int nt = 0; nt < 4; ++nt)
        #pragma unroll
        for (int r = 0; r < 4; ++r) Oacc[nt][r] *= cc[r];
    }
    float ll = 0.f;
    #pragma unroll
    for (int i = 0; i < 16; ++i) {
      float p = exp2x(ps[i] - mrun);       // bounded by 2^11.54 = e^8
      ps[i] = p;
      ll += p;
    }
    ll += __shfl_xor(ll, 16);
    ll += __shfl_xor(ll, 32);
    lrun += ll;

    // P -> bf16 via v_cvt_pk (1 op per 2 values), per-wave swizzled LDS
    #pragma unroll
    for (int mt = 0; mt < 4; ++mt) {
      uint2 pk;
      pk.x = cvtpk(ps[mt*4+0], ps[mt*4+1]);
      pk.y = cvtpk(ps[mt*4+2], ps[mt*4+3]);
      *(uint2*)&Pw[lo*64 + ((((mt<<1) + (hi>>1)) ^ sw) << 3) + ((hi&1) << 2)] = pk;
    }
    asm volatile("s_waitcnt lgkmcnt(0)" ::: "memory");

    short8v pa0 = *(short8v*)&Pw[lo*64 + ((hi ^ sw) << 3)];
    short8v pa1 = *(short8v*)&Pw[lo*64 + (((4 + hi) ^ sw) << 3)];
    __builtin_amdgcn_s_setprio(1);
    #pragma unroll
    for (int nt = 0; nt < 4; ++nt) {
      short8v vb0 = *(const short8v*)&Vc[(nt*16 + lo)*64 + ((hi ^ sw) << 3)];
      short8v vb1 = *(const short8v*)&Vc[(nt*16 + lo)*64 + (((4 + hi) ^ sw) << 3)];
      Oacc[nt] = __builtin_amdgcn_mfma_f32_16x16x32_bf16(pa0, vb0, Oacc[nt], 0,0,0);
      Oacc[nt] = __builtin_amdgcn_mfma_f32_16x16x32_bf16(pa1, vb1, Oacc[nt], 0,0,0);
    }
    __builtin_amdgcn_s_setprio(0);
    cur ^= 1;
  }

  float linv = 1.f / lrun;
  float li[4];
  #pragma unroll
  for (int r = 0; r < 4; ++r) li[r] = __shfl(linv, hi*4 + r);
  const int b = bh >> 2, h = bh & 3;
  short* obp = ob + ((size_t)b * C_ + q0) * L_ + h * D_;
  #pragma unroll
  for (int nt = 0; nt < 4; ++nt)
    #pragma unroll
    for (int r = 0; r < 4; ++r)
      obp[(hi*4 + r) * L_ + nt*16 + lo] = f2bf(Oacc[nt][r] * li[r]);
}

// ---- GEMM2 + LN2 + residual, fused. BM=64, full N=256 per block ----
__global__ __launch_bounds__(256) void gemm2_ln_mfma_kernel(
    const short* __restrict__ ob, const short* __restrict__ W2t,
    const float* __restrict__ b2, const float* __restrict__ g2,
    const float* __restrict__ be2, const float* __restrict__ x,
    float* __restrict__ out) {
  __shared__ short As[64*72];
  __shared__ short Bs[256*72];
  __shared__ float2 red[2][2][32];
  const int tid = threadIdx.x;
  const int w = tid >> 6, l = tid & 63, lo = l & 15, hi = l >> 4;
  const int wr = w >> 1, wc = w & 1;
  const int m0 = blockIdx.x * 64;

  f32x4 acc[2][8];
  #pragma unroll
  for (int m = 0; m < 2; ++m)
    #pragma unroll
    for (int n = 0; n < 8; ++n) acc[m][n] = (f32x4){0.f,0.f,0.f,0.f};

  for (int kt = 0; kt < 4; ++kt) {
    __syncthreads();
    #pragma unroll
    for (int i = 0; i < 2; ++i) {
      int id = tid + i * 256;
      int row = id >> 3, k8 = (id & 7) * 8;
      *(short8v*)&As[row*72 + k8] =
          *(const short8v*)(ob + (size_t)(m0 + row) * 256 + kt*64 + k8);
    }
    #pragma unroll
    for (int i = 0; i < 8; ++i) {
      int id = tid + i * 256;
      int row = id >> 3, k8 = (id & 7) * 8;
      *(short8v*)&Bs[row*72 + k8] =
          *(const short8v*)(W2t + (size_t)row * 256 + kt*64 + k8);
    }
    __syncthreads();
    #pragma unroll
    for (int kk = 0; kk < 2; ++kk) {
      short8v af[2], bf[8];
      #pragma unroll
      for (int m = 0; m < 2; ++m)
        af[m] = *(short8v*)&As[(wr*32 + m*16 + lo)*72 + kk*32 + hi*8];
      #pragma unroll
      for (int n = 0; n < 8; ++n)
        bf[n] = *(short8v*)&Bs[(wc*128 + n*16 + lo)*72 + kk*32 + hi*8];
      #pragma unroll
      for (int m = 0; m < 2; ++m)
        #pragma unroll
        for (int n = 0; n < 8; ++n)
          acc[m][n] = __builtin_amdgcn_mfma_f32_16x16x32_bf16(af[m], bf[n], acc[m][n], 0,0,0);
    }
  }

  float bb[8], gg[8], ee[8];
  #pragma unroll
  for (int n = 0; n < 8; ++n) {
    int col = wc*128 + n*16 + lo;
    bb[n] = b2[col]; gg[n] = g2[col]; ee[n] = be2[col];
  }
  float ps[2][4], pq[2][4];
  #pragma unroll
  for (int m = 0; m < 2; ++m)
    #pragma unroll
    for (int r = 0; r < 4; ++r) {
      float s = 0.f, s2 = 0.f;
      #pragma unroll
      for (int n = 0; n < 8; ++n) {
        float v = acc[m][n][r] + bb[n];
        acc[m][n][r] = v;
        s += v; s2 += v*v;
      }
      ps[m][r] = s; pq[m][r] = s2;
    }
  #pragma unroll
  for (int off = 1; off < 16; off <<= 1)
    #pragma unroll
    for (int m = 0; m < 2; ++m)
      #pragma unroll
      for (int r = 0; r < 4; ++r) {
        ps[m][r] += __shfl_xor(ps[m][r], off);
        pq[m][r] += __shfl_xor(pq[m][r], off);
      }
  if (lo == 0)
    #pragma unroll
    for (int m = 0; m < 2; ++m)
      #pragma unroll
      for (int r = 0; r < 4; ++r)
        red[wr][wc][m*16 + hi*4 + r] = make_float2(ps[m][r], pq[m][r]);
  __syncthreads();

  #pragma unroll
  for (int m = 0; m < 2; ++m)
    #pragma unroll
    for (int r = 0; r < 4; ++r) {
      float2 t0 = red[wr][0][m*16 + hi*4 + r];
      float2 t1 = red[wr][1][m*16 + hi*4 + r];
      float s = t0.x + t1.x, s2 = t0.y + t1.y;
      float mu  = s * (1.f / L_);
      float var = s2 * (1.f / L_) - mu * mu;
      float rs  = rsqrtf(var + 1e-5f);
      const int grow = m0 + wr*32 + m*16 + hi*4 + r;
      const float* xr = x + (size_t)grow * L_ + wc*128;
      float* orow = out + (size_t)grow * L_ + wc*128;
      #pragma unroll
      for (int n = 0; n < 8; ++n)
        orow[n*16 + lo] = (acc[m][n][r] - mu) * rs * gg[n] + ee[n] + xr[n*16 + lo];
    }
}

extern "C" void kernel_launch(void* const* d_in, const int* in_sizes, int n_in,
                              void* d_out, int out_size, void* d_ws, size_t ws_size,
                              hipStream_t stream) {
  const float* x   = (const float*)d_in[0];
  const float* W1  = (const float*)d_in[1];
  const float* b1  = (const float*)d_in[2];
  const float* g1  = (const float*)d_in[3];
  const float* be1 = (const float*)d_in[4];
  const float* W2  = (const float*)d_in[5];
  const float* b2  = (const float*)d_in[6];
  const float* g2  = (const float*)d_in[7];
  const float* be2 = (const float*)d_in[8];
  float* out = (float*)d_out;

  const size_t HDSZ = (size_t)B_ * H_ * C_ * D_;   // 4,194,304
  short* W1t = (short*)d_ws;          // [768][256] bf16
  short* W2t = W1t + (size_t)L_ * E_; // [256][256] bf16
  short* y1  = W2t + (size_t)L_ * L_; // [M][768] bf16
  short* Qg  = y1  + (size_t)M_ * E_; // [bh][c][64] (pre-scaled, log2 domain)
  short* Kg  = Qg  + HDSZ;            // [bh][c][64] swizzled
  short* Vtg = Kg  + HDSZ;            // [bh][64][c] swizzled
  short* obm = Vtg + HDSZ;            // [M][256] bf16

  transpose_w_kernel<<<dim3(8, 24), 256, 0, stream>>>(W1, W1t, L_, E_);
  transpose_w_kernel<<<dim3(8, 8),  256, 0, stream>>>(W2, W2t, L_, L_);
  gemm1_mfma_kernel<<<dim3(M_ / 128, E_ / 128), 256, 0, stream>>>(x, W1t, b1, y1);
  ln1_kernel<<<M_ / 64, 256, 0, stream>>>(y1, g1, be1, Qg, Kg, Vtg);
  attn_mfma_kernel<<<dim3(32, 32), 256, 0, stream>>>(Qg, Kg, Vtg, obm);
  gemm2_ln_mfma_kernel<<<M_ / 64, 256, 0, stream>>>(obm, W2t, b2, g2, be2, x, out);
}

// Round 6
// 118.434 us; speedup vs baseline: 11.6197x; 1.0429x over previous
//
#include <hip/hip_runtime.h>
#include <hip/hip_bf16.h>

#define B_ 8
#define C_ 2048
#define L_ 256
#define E_ 768
#define H_ 4
#define D_ 64
#define M_ (B_*C_)   // 16384 rows

typedef __attribute__((ext_vector_type(8))) short short8v;   // 8 bf16 (4 VGPR) MFMA A/B frag
typedef __attribute__((ext_vector_type(4))) short short4v;   // 8B packed store
typedef __attribute__((ext_vector_type(4))) float f32x4;     // MFMA C/D frag

__device__ __forceinline__ short f2bf(float f) {             // f32 -> bf16 RNE
  union { float f; unsigned u; } v; v.f = f;
  unsigned r = v.u + 0x7FFFu + ((v.u >> 16) & 1u);
  return (short)(r >> 16);
}
__device__ __forceinline__ float bf2f(short s) {
  union { unsigned u; float f; } v; v.u = ((unsigned)(unsigned short)s) << 16;
  return v.f;
}
// two f32 -> packed bf16x2 in one VALU op (gfx950; no builtin, m240)
__device__ __forceinline__ unsigned cvtpk(float a, float b) {
  unsigned r;
  asm("v_cvt_pk_bf16_f32 %0, %1, %2" : "=v"(r) : "v"(a), "v"(b));
  return r;
}
__device__ __forceinline__ float exp2x(float x) {            // 2^x, single v_exp_f32
  float r;
  asm("v_exp_f32 %0, %1" : "=v"(r) : "v"(x));
  return r;
}

// async global->LDS, 16B per lane; LDS dest = uniform base + lane*16 (m104)
__device__ __forceinline__ void gll16(const void* g, void* l) {
  __builtin_amdgcn_global_load_lds(
      (const __attribute__((address_space(1))) unsigned int*)g,
      (__attribute__((address_space(3))) unsigned int*)l, 16, 0, 0);
}

// ---- prep: W f32 [K][N] -> Wt bf16 [N][K] via 32x32 LDS tiles ----
__global__ __launch_bounds__(256) void transpose_w_kernel(const float* __restrict__ W,
                                                          short* __restrict__ Wt,
                                                          int K, int N) {
  __shared__ float ld[32][33];
  const int k0 = blockIdx.x * 32, n0 = blockIdx.y * 32;
  const int tx = threadIdx.x & 31, ty = threadIdx.x >> 5;
  #pragma unroll
  for (int j = 0; j < 4; ++j)
    ld[ty + j*8][tx] = W[(size_t)(k0 + ty + j*8) * N + n0 + tx];
  __syncthreads();
  const int r  = threadIdx.x >> 3;
  const int c0 = (threadIdx.x & 7) * 4;
  short4v o;
  o[0]=f2bf(ld[c0+0][r]); o[1]=f2bf(ld[c0+1][r]);
  o[2]=f2bf(ld[c0+2][r]); o[3]=f2bf(ld[c0+3][r]);
  *(short4v*)(Wt + (size_t)(n0 + r) * K + k0 + c0) = o;
}

// ---- GEMM1: y1[M][768] = x[M][256] @ W1 (+b1); x converted in staging ----
__global__ __launch_bounds__(256) void gemm1_mfma_kernel(
    const float* __restrict__ x, const short* __restrict__ W1t,
    const float* __restrict__ b1, short* __restrict__ y1) {
  __shared__ short As[128*72];
  __shared__ short Bs[128*72];
  const int tid = threadIdx.x;
  const int w = tid >> 6, l = tid & 63, lo = l & 15, hi = l >> 4;
  const int wr = w >> 1, wc = w & 1;
  const int m0 = blockIdx.x * 128, n0 = blockIdx.y * 128;

  f32x4 acc[4][4];
  #pragma unroll
  for (int m = 0; m < 4; ++m)
    #pragma unroll
    for (int n = 0; n < 4; ++n) acc[m][n] = (f32x4){0.f,0.f,0.f,0.f};

  for (int kt = 0; kt < 4; ++kt) {
    __syncthreads();
    #pragma unroll
    for (int i = 0; i < 4; ++i) {
      int id = tid + i * 256;
      int row = id >> 3, k8 = (id & 7) * 8;
      const float* ap = x + (size_t)(m0 + row) * 256 + kt*64 + k8;
      float4 a0 = ((const float4*)ap)[0], a1 = ((const float4*)ap)[1];
      uint4 pk;
      pk.x = cvtpk(a0.x, a0.y); pk.y = cvtpk(a0.z, a0.w);
      pk.z = cvtpk(a1.x, a1.y); pk.w = cvtpk(a1.z, a1.w);
      *(uint4*)&As[row*72 + k8] = pk;
      *(short8v*)&Bs[row*72 + k8] =
          *(const short8v*)(W1t + (size_t)(n0 + row) * 256 + kt*64 + k8);
    }
    __syncthreads();
    #pragma unroll
    for (int kk = 0; kk < 2; ++kk) {
      short8v af[4], bf[4];
      #pragma unroll
      for (int m = 0; m < 4; ++m)
        af[m] = *(short8v*)&As[(wr*64 + m*16 + lo)*72 + kk*32 + hi*8];
      #pragma unroll
      for (int n = 0; n < 4; ++n)
        bf[n] = *(short8v*)&Bs[(wc*64 + n*16 + lo)*72 + kk*32 + hi*8];
      #pragma unroll
      for (int m = 0; m < 4; ++m)
        #pragma unroll
        for (int n = 0; n < 4; ++n)
          acc[m][n] = __builtin_amdgcn_mfma_f32_16x16x32_bf16(af[m], bf[n], acc[m][n], 0,0,0);
    }
  }

  float bb[4];
  #pragma unroll
  for (int n = 0; n < 4; ++n) bb[n] = b1[n0 + wc*64 + n*16 + lo];
  #pragma unroll
  for (int m = 0; m < 4; ++m) {
    const int gr = m0 + wr*64 + m*16 + hi*4;
    #pragma unroll
    for (int r = 0; r < 4; ++r) {
      short* yp = y1 + (size_t)(gr + r) * E_ + n0 + wc*64;
      #pragma unroll
      for (int n = 0; n < 4; ++n)
        yp[n*16 + lo] = f2bf(acc[m][n][r] + bb[n]);
    }
  }
}

// ---- LN1: y1 -> Q (x 0.125*log2e, linear), K + Vt PRE-SWIZZLED for attn ----
__global__ __launch_bounds__(256) void ln1_kernel(
    const short* __restrict__ y1, const float* __restrict__ g1,
    const float* __restrict__ be1,
    short* __restrict__ Qg, short* __restrict__ Kg, short* __restrict__ Vtg) {
  __shared__ float mu_s[64], rs_s[64];
  __shared__ short Vlds[64][264];
  const int tid = threadIdx.x;
  const int w = tid >> 6, l = tid & 63;
  const int b = blockIdx.x >> 5;
  const int c0 = (blockIdx.x & 31) * 64;
  const size_t rowbase = (size_t)b * C_ + c0;

  for (int rr = w*16; rr < w*16 + 16; ++rr) {
    const short* yr = y1 + (rowbase + rr) * E_ + l * 12;
    float s = 0.f, s2 = 0.f;
    #pragma unroll
    for (int j = 0; j < 3; ++j) {
      short4v v = *(const short4v*)(yr + j*4);
      #pragma unroll
      for (int t = 0; t < 4; ++t) { float f = bf2f(v[t]); s += f; s2 += f*f; }
    }
    #pragma unroll
    for (int off = 1; off < 64; off <<= 1) {
      s  += __shfl_xor(s, off);
      s2 += __shfl_xor(s2, off);
    }
    if (l == 0) {
      float mu = s * (1.f / E_);
      float var = s2 * (1.f / E_) - mu * mu;
      mu_s[rr] = mu;
      rs_s[rr] = rsqrtf(var + 1e-5f);
    }
  }
  __syncthreads();

  // emit Q (linear, log2-domain scale) and K (swizzled)
  {
    const int chunk = tid & 63, e0 = chunk * 8;
    float gg[8], ee[8];
    #pragma unroll
    for (int j = 0; j < 8; ++j) { gg[j] = g1[e0+j]; ee[j] = be1[e0+j]; }
    const int isQ = (e0 < 256);
    const int eb  = isQ ? e0 : e0 - 256;
    const int h = eb >> 6, d0 = eb & 63;
    short* dstQ = Qg + ((size_t)(b*H_ + h) * C_ + c0) * D_ + d0;
    short* dstK = Kg + ((size_t)(b*H_ + h) * C_ + c0) * D_;
    const float qs = isQ ? 0.18033688011f : 1.f;   // 0.125 * log2(e)
    for (int rg = 0; rg < 16; ++rg) {
      int rr = rg*4 + (tid >> 6);
      short8v v = *(const short8v*)(y1 + (rowbase + rr) * E_ + e0);
      float mu = mu_s[rr], rs = rs_s[rr];
      short8v o;
      #pragma unroll
      for (int j = 0; j < 8; ++j)
        o[j] = f2bf(((bf2f(v[j]) - mu) * rs * gg[j] + ee[j]) * qs);
      if (isQ) *(short8v*)(dstQ + (size_t)rr * D_) = o;
      else     *(short8v*)(dstK + (size_t)rr * D_ + ((((d0>>3) ^ (rr&7)) << 3))) = o;
    }
  }
  // emit V into LDS
  {
    const int chunk = tid & 31, e0 = 512 + chunk * 8;
    float gg[8], ee[8];
    #pragma unroll
    for (int j = 0; j < 8; ++j) { gg[j] = g1[e0+j]; ee[j] = be1[e0+j]; }
    for (int rg = 0; rg < 8; ++rg) {
      int rr = rg*8 + (tid >> 5);
      short8v v = *(const short8v*)(y1 + (rowbase + rr) * E_ + e0);
      float mu = mu_s[rr], rs = rs_s[rr];
      short8v o;
      #pragma unroll
      for (int j = 0; j < 8; ++j)
        o[j] = f2bf((bf2f(v[j]) - mu) * rs * gg[j] + ee[j]);
      *(short8v*)&Vlds[rr][chunk * 8] = o;
    }
  }
  __syncthreads();
  // write Vt swizzled: row = d, chunk c8 -> c8 ^ (d&7) within this 64-c window
  {
    const int h = tid >> 6, d = tid & 63;
    short* dst = Vtg + ((size_t)(b*H_ + h) * D_ + d) * C_ + c0;
    #pragma unroll
    for (int c8 = 0; c8 < 8; ++c8) {
      short8v vv;
      #pragma unroll
      for (int j = 0; j < 8; ++j) vv[j] = Vlds[c8*8 + j][tid];
      *(short8v*)(dst + ((c8 ^ (d&7)) << 3)) = vv;
    }
  }
}

// ---- MFMA flash attention: 8 waves / 128 q-rows per block. Staged K/V tile
//      amortized over 2x compute vs R4; per-wave inner code unchanged. ----
__global__ __launch_bounds__(512, 4) void attn_mfma_kernel(
    const short* __restrict__ Qg, const short* __restrict__ Kg,
    const short* __restrict__ Vtg, short* __restrict__ ob) {
  __shared__ short Ks[2][4096];     // [buf][64 keys x 64 d], swizzled image
  __shared__ short Vs[2][4096];     // [buf][64 d x 64 keys], swizzled image
  __shared__ short Ps[8][1024];     // per-wave P tile [16 q][64 keys], swizzled
  const int tid = threadIdx.x;
  const int w  = tid >> 6;          // 0..7
  const int l  = tid & 63, lo = l & 15, hi = l >> 4;
  const int sw = lo & 7;
  const int qt = blockIdx.x, bh = blockIdx.y;
  const size_t hd = (size_t)bh * (C_ * D_);
  const int q0 = qt * 128 + w * 16;

  const short8v bq0 = *(const short8v*)(Qg + hd + (size_t)(q0+lo)*D_ + hi*8);
  const short8v bq1 = *(const short8v*)(Qg + hd + (size_t)(q0+lo)*D_ + 32 + hi*8);

  // staging geometry: wave w DMAs segment w (1KB) of K and of V per tile
  const short* Ktile = Kg + hd;
  const short* Vrow  = Vtg + hd;
  const int kOff = w*512 + l*8;
  const size_t vOff = (size_t)(w*8 + (l>>3)) * C_ + (l&7)*8;

  float mrun = -3.0e38f, lrun = 0.f;     // log2-domain running max
  f32x4 Oacc[4] = {{0,0,0,0},{0,0,0,0},{0,0,0,0},{0,0,0,0}};
  short* Pw = &Ps[w][0];

  gll16(Ktile + kOff, &Ks[0][w*512]);
  gll16(Vrow + vOff,  &Vs[0][w*512]);

  int cur = 0;
  for (int kt = 0; kt < 32; ++kt) {
    __builtin_amdgcn_s_barrier();          // all waves done reading buf[cur^1]
    if (kt != 31) {                         // stage kt+1 -> buf[cur^1]
      const short* kn = Ktile + (size_t)(kt+1) * 4096;
      const short* vn = Vrow  + (size_t)(kt+1) * 64;
      gll16(kn + kOff, &Ks[cur^1][w*512]);
      gll16(vn + vOff, &Vs[cur^1][w*512]);
      asm volatile("s_waitcnt vmcnt(2)" ::: "memory");  // kt landed; kt+1 in flight
    } else {
      asm volatile("s_waitcnt vmcnt(0)" ::: "memory");
    }
    __builtin_amdgcn_s_barrier();          // buf[cur] ready for everyone
    const short* Kc = &Ks[cur][0];
    const short* Vc = &Vs[cur][0];

    f32x4 st[4];
    __builtin_amdgcn_s_setprio(1);
    #pragma unroll
    for (int mt = 0; mt < 4; ++mt) {
      short8v ka = *(const short8v*)&Kc[(mt*16 + lo)*64 + ((hi ^ sw) << 3)];
      short8v kb = *(const short8v*)&Kc[(mt*16 + lo)*64 + (((4 + hi) ^ sw) << 3)];
      f32x4 z = {0.f, 0.f, 0.f, 0.f};
      z      = __builtin_amdgcn_mfma_f32_16x16x32_bf16(ka, bq0, z, 0, 0, 0);
      st[mt] = __builtin_amdgcn_mfma_f32_16x16x32_bf16(kb, bq1, z, 0, 0, 0);
    }
    __builtin_amdgcn_s_setprio(0);

    // online softmax, log2 domain; defer threshold 8*log2(e)
    float ps[16];
    float tmax = -3.0e38f;
    #pragma unroll
    for (int mt = 0; mt < 4; ++mt)
      #pragma unroll
      for (int r = 0; r < 4; ++r) {
        float v = st[mt][r];
        ps[mt*4 + r] = v;
        tmax = fmaxf(tmax, v);
      }
    tmax = fmaxf(tmax, __shfl_xor(tmax, 16));
    tmax = fmaxf(tmax, __shfl_xor(tmax, 32));
    if (__any(tmax > mrun + 11.5415603f)) {
      float mnew = fmaxf(mrun, tmax);
      float corr = exp2x(mrun - mnew);
      mrun = mnew;
      lrun *= corr;
      float cc[4];
      #pragma unroll
      for (int r = 0; r < 4; ++r) cc[r] = __shfl(corr, hi*4 + r);
      #pragma unroll
      for (int nt = 0; nt < 4; ++nt)
        #pragma unroll
        for (int r = 0; r < 4; ++r) Oacc[nt][r] *= cc[r];
    }
    float ll = 0.f;
    #pragma unroll
    for (int i = 0; i < 16; ++i) {
      float p = exp2x(ps[i] - mrun);       // bounded by 2^11.54 = e^8
      ps[i] = p;
      ll += p;
    }
    ll += __shfl_xor(ll, 16);
    ll += __shfl_xor(ll, 32);
    lrun += ll;

    // P -> bf16 via v_cvt_pk, per-wave swizzled LDS
    #pragma unroll
    for (int mt = 0; mt < 4; ++mt) {
      uint2 pk;
      pk.x = cvtpk(ps[mt*4+0], ps[mt*4+1]);
      pk.y = cvtpk(ps[mt*4+2], ps[mt*4+3]);
      *(uint2*)&Pw[lo*64 + ((((mt<<1) + (hi>>1)) ^ sw) << 3) + ((hi&1) << 2)] = pk;
    }
    asm volatile("s_waitcnt lgkmcnt(0)" ::: "memory");   // same-wave P RAW

    short8v pa0 = *(short8v*)&Pw[lo*64 + ((hi ^ sw) << 3)];
    short8v pa1 = *(short8v*)&Pw[lo*64 + (((4 + hi) ^ sw) << 3)];
    __builtin_amdgcn_s_setprio(1);
    #pragma unroll
    for (int nt = 0; nt < 4; ++nt) {
      short8v vb0 = *(const short8v*)&Vc[(nt*16 + lo)*64 + ((hi ^ sw) << 3)];
      short8v vb1 = *(const short8v*)&Vc[(nt*16 + lo)*64 + (((4 + hi) ^ sw) << 3)];
      Oacc[nt] = __builtin_amdgcn_mfma_f32_16x16x32_bf16(pa0, vb0, Oacc[nt], 0,0,0);
      Oacc[nt] = __builtin_amdgcn_mfma_f32_16x16x32_bf16(pa1, vb1, Oacc[nt], 0,0,0);
    }
    __builtin_amdgcn_s_setprio(0);
    cur ^= 1;
  }

  float linv = 1.f / lrun;
  float li[4];
  #pragma unroll
  for (int r = 0; r < 4; ++r) li[r] = __shfl(linv, hi*4 + r);
  const int b = bh >> 2, h = bh & 3;
  short* obp = ob + ((size_t)b * C_ + q0) * L_ + h * D_;
  #pragma unroll
  for (int nt = 0; nt < 4; ++nt)
    #pragma unroll
    for (int r = 0; r < 4; ++r)
      obp[(hi*4 + r) * L_ + nt*16 + lo] = f2bf(Oacc[nt][r] * li[r]);
}

// ---- GEMM2 + LN2 + residual, fused. BM=64, full N=256 per block ----
__global__ __launch_bounds__(256) void gemm2_ln_mfma_kernel(
    const short* __restrict__ ob, const short* __restrict__ W2t,
    const float* __restrict__ b2, const float* __restrict__ g2,
    const float* __restrict__ be2, const float* __restrict__ x,
    float* __restrict__ out) {
  __shared__ short As[64*72];
  __shared__ short Bs[256*72];
  __shared__ float2 red[2][2][32];
  const int tid = threadIdx.x;
  const int w = tid >> 6, l = tid & 63, lo = l & 15, hi = l >> 4;
  const int wr = w >> 1, wc = w & 1;
  const int m0 = blockIdx.x * 64;

  f32x4 acc[2][8];
  #pragma unroll
  for (int m = 0; m < 2; ++m)
    #pragma unroll
    for (int n = 0; n < 8; ++n) acc[m][n] = (f32x4){0.f,0.f,0.f,0.f};

  for (int kt = 0; kt < 4; ++kt) {
    __syncthreads();
    #pragma unroll
    for (int i = 0; i < 2; ++i) {
      int id = tid + i * 256;
      int row = id >> 3, k8 = (id & 7) * 8;
      *(short8v*)&As[row*72 + k8] =
          *(const short8v*)(ob + (size_t)(m0 + row) * 256 + kt*64 + k8);
    }
    #pragma unroll
    for (int i = 0; i < 8; ++i) {
      int id = tid + i * 256;
      int row = id >> 3, k8 = (id & 7) * 8;
      *(short8v*)&Bs[row*72 + k8] =
          *(const short8v*)(W2t + (size_t)row * 256 + kt*64 + k8);
    }
    __syncthreads();
    #pragma unroll
    for (int kk = 0; kk < 2; ++kk) {
      short8v af[2], bf[8];
      #pragma unroll
      for (int m = 0; m < 2; ++m)
        af[m] = *(short8v*)&As[(wr*32 + m*16 + lo)*72 + kk*32 + hi*8];
      #pragma unroll
      for (int n = 0; n < 8; ++n)
        bf[n] = *(short8v*)&Bs[(wc*128 + n*16 + lo)*72 + kk*32 + hi*8];
      #pragma unroll
      for (int m = 0; m < 2; ++m)
        #pragma unroll
        for (int n = 0; n < 8; ++n)
          acc[m][n] = __builtin_amdgcn_mfma_f32_16x16x32_bf16(af[m], bf[n], acc[m][n], 0,0,0);
    }
  }

  float bb[8], gg[8], ee[8];
  #pragma unroll
  for (int n = 0; n < 8; ++n) {
    int col = wc*128 + n*16 + lo;
    bb[n] = b2[col]; gg[n] = g2[col]; ee[n] = be2[col];
  }
  float ps[2][4], pq[2][4];
  #pragma unroll
  for (int m = 0; m < 2; ++m)
    #pragma unroll
    for (int r = 0; r < 4; ++r) {
      float s = 0.f, s2 = 0.f;
      #pragma unroll
      for (int n = 0; n < 8; ++n) {
        float v = acc[m][n][r] + bb[n];
        acc[m][n][r] = v;
        s += v; s2 += v*v;
      }
      ps[m][r] = s; pq[m][r] = s2;
    }
  #pragma unroll
  for (int off = 1; off < 16; off <<= 1)
    #pragma unroll
    for (int m = 0; m < 2; ++m)
      #pragma unroll
      for (int r = 0; r < 4; ++r) {
        ps[m][r] += __shfl_xor(ps[m][r], off);
        pq[m][r] += __shfl_xor(pq[m][r], off);
      }
  if (lo == 0)
    #pragma unroll
    for (int m = 0; m < 2; ++m)
      #pragma unroll
      for (int r = 0; r < 4; ++r)
        red[wr][wc][m*16 + hi*4 + r] = make_float2(ps[m][r], pq[m][r]);
  __syncthreads();

  #pragma unroll
  for (int m = 0; m < 2; ++m)
    #pragma unroll
    for (int r = 0; r < 4; ++r) {
      float2 t0 = red[wr][0][m*16 + hi*4 + r];
      float2 t1 = red[wr][1][m*16 + hi*4 + r];
      float s = t0.x + t1.x, s2 = t0.y + t1.y;
      float mu  = s * (1.f / L_);
      float var = s2 * (1.f / L_) - mu * mu;
      float rs  = rsqrtf(var + 1e-5f);
      const int grow = m0 + wr*32 + m*16 + hi*4 + r;
      const float* xr = x + (size_t)grow * L_ + wc*128;
      float* orow = out + (size_t)grow * L_ + wc*128;
      #pragma unroll
      for (int n = 0; n < 8; ++n)
        orow[n*16 + lo] = (acc[m][n][r] - mu) * rs * gg[n] + ee[n] + xr[n*16 + lo];
    }
}

extern "C" void kernel_launch(void* const* d_in, const int* in_sizes, int n_in,
                              void* d_out, int out_size, void* d_ws, size_t ws_size,
                              hipStream_t stream) {
  const float* x   = (const float*)d_in[0];
  const float* W1  = (const float*)d_in[1];
  const float* b1  = (const float*)d_in[2];
  const float* g1  = (const float*)d_in[3];
  const float* be1 = (const float*)d_in[4];
  const float* W2  = (const float*)d_in[5];
  const float* b2  = (const float*)d_in[6];
  const float* g2  = (const float*)d_in[7];
  const float* be2 = (const float*)d_in[8];
  float* out = (float*)d_out;

  const size_t HDSZ = (size_t)B_ * H_ * C_ * D_;   // 4,194,304
  short* W1t = (short*)d_ws;          // [768][256] bf16
  short* W2t = W1t + (size_t)L_ * E_; // [256][256] bf16
  short* y1  = W2t + (size_t)L_ * L_; // [M][768] bf16
  short* Qg  = y1  + (size_t)M_ * E_; // [bh][c][64] (pre-scaled, log2 domain)
  short* Kg  = Qg  + HDSZ;            // [bh][c][64] swizzled
  short* Vtg = Kg  + HDSZ;            // [bh][64][c] swizzled
  short* obm = Vtg + HDSZ;            // [M][256] bf16

  transpose_w_kernel<<<dim3(8, 24), 256, 0, stream>>>(W1, W1t, L_, E_);
  transpose_w_kernel<<<dim3(8, 8),  256, 0, stream>>>(W2, W2t, L_, L_);
  gemm1_mfma_kernel<<<dim3(M_ / 128, E_ / 128), 256, 0, stream>>>(x, W1t, b1, y1);
  ln1_kernel<<<M_ / 64, 256, 0, stream>>>(y1, g1, be1, Qg, Kg, Vtg);
  attn_mfma_kernel<<<dim3(C_ / 128, 32), 512, 0, stream>>>(Qg, Kg, Vtg, obm);
  gemm2_ln_mfma_kernel<<<M_ / 64, 256, 0, stream>>>(obm, W2t, b2, g2, be2, x, out);
}

// Round 7
// 116.130 us; speedup vs baseline: 11.8502x; 1.0198x over previous
//
#include <hip/hip_runtime.h>
#include <hip/hip_bf16.h>

#define B_ 8
#define C_ 2048
#define L_ 256
#define E_ 768
#define H_ 4
#define D_ 64
#define M_ (B_*C_)   // 16384 rows

typedef __attribute__((ext_vector_type(8))) short short8v;   // 8 bf16 (4 VGPR) MFMA A/B frag
typedef __attribute__((ext_vector_type(4))) short short4v;   // 8B packed store
typedef __attribute__((ext_vector_type(4))) float f32x4;     // MFMA C/D frag

__device__ __forceinline__ short f2bf(float f) {             // f32 -> bf16 RNE
  union { float f; unsigned u; } v; v.f = f;
  unsigned r = v.u + 0x7FFFu + ((v.u >> 16) & 1u);
  return (short)(r >> 16);
}
__device__ __forceinline__ float bf2f(short s) {
  union { unsigned u; float f; } v; v.u = ((unsigned)(unsigned short)s) << 16;
  return v.f;
}
// two f32 -> packed bf16x2 in one VALU op (gfx950; no builtin, m240)
__device__ __forceinline__ unsigned cvtpk(float a, float b) {
  unsigned r;
  asm("v_cvt_pk_bf16_f32 %0, %1, %2" : "=v"(r) : "v"(a), "v"(b));
  return r;
}
__device__ __forceinline__ float exp2x(float x) {            // 2^x, single v_exp_f32
  float r;
  asm("v_exp_f32 %0, %1" : "=v"(r) : "v"(x));
  return r;
}

// async global->LDS, 16B per lane; LDS dest = uniform base + lane*16 (m104)
__device__ __forceinline__ void gll16(const void* g, void* l) {
  __builtin_amdgcn_global_load_lds(
      (const __attribute__((address_space(1))) unsigned int*)g,
      (__attribute__((address_space(3))) unsigned int*)l, 16, 0, 0);
}

// ---- prep: W f32 [K][N] -> Wt bf16 [N][K] via 32x32 LDS tiles ----
__global__ __launch_bounds__(256) void transpose_w_kernel(const float* __restrict__ W,
                                                          short* __restrict__ Wt,
                                                          int K, int N) {
  __shared__ float ld[32][33];
  const int k0 = blockIdx.x * 32, n0 = blockIdx.y * 32;
  const int tx = threadIdx.x & 31, ty = threadIdx.x >> 5;
  #pragma unroll
  for (int j = 0; j < 4; ++j)
    ld[ty + j*8][tx] = W[(size_t)(k0 + ty + j*8) * N + n0 + tx];
  __syncthreads();
  const int r  = threadIdx.x >> 3;
  const int c0 = (threadIdx.x & 7) * 4;
  short4v o;
  o[0]=f2bf(ld[c0+0][r]); o[1]=f2bf(ld[c0+1][r]);
  o[2]=f2bf(ld[c0+2][r]); o[3]=f2bf(ld[c0+3][r]);
  *(short4v*)(Wt + (size_t)(n0 + r) * K + k0 + c0) = o;
}

// ---- GEMM1: y1[M][768] = x[M][256] @ W1 (+b1); x converted in staging ----
__global__ __launch_bounds__(256) void gemm1_mfma_kernel(
    const float* __restrict__ x, const short* __restrict__ W1t,
    const float* __restrict__ b1, short* __restrict__ y1) {
  __shared__ short As[128*72];
  __shared__ short Bs[128*72];
  const int tid = threadIdx.x;
  const int w = tid >> 6, l = tid & 63, lo = l & 15, hi = l >> 4;
  const int wr = w >> 1, wc = w & 1;
  const int m0 = blockIdx.x * 128, n0 = blockIdx.y * 128;

  f32x4 acc[4][4];
  #pragma unroll
  for (int m = 0; m < 4; ++m)
    #pragma unroll
    for (int n = 0; n < 4; ++n) acc[m][n] = (f32x4){0.f,0.f,0.f,0.f};

  for (int kt = 0; kt < 4; ++kt) {
    __syncthreads();
    #pragma unroll
    for (int i = 0; i < 4; ++i) {
      int id = tid + i * 256;
      int row = id >> 3, k8 = (id & 7) * 8;
      const float* ap = x + (size_t)(m0 + row) * 256 + kt*64 + k8;
      float4 a0 = ((const float4*)ap)[0], a1 = ((const float4*)ap)[1];
      uint4 pk;
      pk.x = cvtpk(a0.x, a0.y); pk.y = cvtpk(a0.z, a0.w);
      pk.z = cvtpk(a1.x, a1.y); pk.w = cvtpk(a1.z, a1.w);
      *(uint4*)&As[row*72 + k8] = pk;
      *(short8v*)&Bs[row*72 + k8] =
          *(const short8v*)(W1t + (size_t)(n0 + row) * 256 + kt*64 + k8);
    }
    __syncthreads();
    #pragma unroll
    for (int kk = 0; kk < 2; ++kk) {
      short8v af[4], bf[4];
      #pragma unroll
      for (int m = 0; m < 4; ++m)
        af[m] = *(short8v*)&As[(wr*64 + m*16 + lo)*72 + kk*32 + hi*8];
      #pragma unroll
      for (int n = 0; n < 4; ++n)
        bf[n] = *(short8v*)&Bs[(wc*64 + n*16 + lo)*72 + kk*32 + hi*8];
      #pragma unroll
      for (int m = 0; m < 4; ++m)
        #pragma unroll
        for (int n = 0; n < 4; ++n)
          acc[m][n] = __builtin_amdgcn_mfma_f32_16x16x32_bf16(af[m], bf[n], acc[m][n], 0,0,0);
    }
  }

  float bb[4];
  #pragma unroll
  for (int n = 0; n < 4; ++n) bb[n] = b1[n0 + wc*64 + n*16 + lo];
  #pragma unroll
  for (int m = 0; m < 4; ++m) {
    const int gr = m0 + wr*64 + m*16 + hi*4;
    #pragma unroll
    for (int r = 0; r < 4; ++r) {
      short* yp = y1 + (size_t)(gr + r) * E_ + n0 + wc*64;
      #pragma unroll
      for (int n = 0; n < 4; ++n)
        yp[n*16 + lo] = f2bf(acc[m][n][r] + bb[n]);
    }
  }
}

// ---- LN1: y1 -> Q (x 0.125*log2e, linear), K + Vt PRE-SWIZZLED for attn ----
__global__ __launch_bounds__(256) void ln1_kernel(
    const short* __restrict__ y1, const float* __restrict__ g1,
    const float* __restrict__ be1,
    short* __restrict__ Qg, short* __restrict__ Kg, short* __restrict__ Vtg) {
  __shared__ float mu_s[64], rs_s[64];
  __shared__ short Vlds[64][264];
  const int tid = threadIdx.x;
  const int w = tid >> 6, l = tid & 63;
  const int b = blockIdx.x >> 5;
  const int c0 = (blockIdx.x & 31) * 64;
  const size_t rowbase = (size_t)b * C_ + c0;

  for (int rr = w*16; rr < w*16 + 16; ++rr) {
    const short* yr = y1 + (rowbase + rr) * E_ + l * 12;
    float s = 0.f, s2 = 0.f;
    #pragma unroll
    for (int j = 0; j < 3; ++j) {
      short4v v = *(const short4v*)(yr + j*4);
      #pragma unroll
      for (int t = 0; t < 4; ++t) { float f = bf2f(v[t]); s += f; s2 += f*f; }
    }
    #pragma unroll
    for (int off = 1; off < 64; off <<= 1) {
      s  += __shfl_xor(s, off);
      s2 += __shfl_xor(s2, off);
    }
    if (l == 0) {
      float mu = s * (1.f / E_);
      float var = s2 * (1.f / E_) - mu * mu;
      mu_s[rr] = mu;
      rs_s[rr] = rsqrtf(var + 1e-5f);
    }
  }
  __syncthreads();

  // emit Q (linear, log2-domain scale) and K (swizzled)
  {
    const int chunk = tid & 63, e0 = chunk * 8;
    float gg[8], ee[8];
    #pragma unroll
    for (int j = 0; j < 8; ++j) { gg[j] = g1[e0+j]; ee[j] = be1[e0+j]; }
    const int isQ = (e0 < 256);
    const int eb  = isQ ? e0 : e0 - 256;
    const int h = eb >> 6, d0 = eb & 63;
    short* dstQ = Qg + ((size_t)(b*H_ + h) * C_ + c0) * D_ + d0;
    short* dstK = Kg + ((size_t)(b*H_ + h) * C_ + c0) * D_;
    const float qs = isQ ? 0.18033688011f : 1.f;   // 0.125 * log2(e)
    for (int rg = 0; rg < 16; ++rg) {
      int rr = rg*4 + (tid >> 6);
      short8v v = *(const short8v*)(y1 + (rowbase + rr) * E_ + e0);
      float mu = mu_s[rr], rs = rs_s[rr];
      short8v o;
      #pragma unroll
      for (int j = 0; j < 8; ++j)
        o[j] = f2bf(((bf2f(v[j]) - mu) * rs * gg[j] + ee[j]) * qs);
      if (isQ) *(short8v*)(dstQ + (size_t)rr * D_) = o;
      else     *(short8v*)(dstK + (size_t)rr * D_ + ((((d0>>3) ^ (rr&7)) << 3))) = o;
    }
  }
  // emit V into LDS
  {
    const int chunk = tid & 31, e0 = 512 + chunk * 8;
    float gg[8], ee[8];
    #pragma unroll
    for (int j = 0; j < 8; ++j) { gg[j] = g1[e0+j]; ee[j] = be1[e0+j]; }
    for (int rg = 0; rg < 8; ++rg) {
      int rr = rg*8 + (tid >> 5);
      short8v v = *(const short8v*)(y1 + (rowbase + rr) * E_ + e0);
      float mu = mu_s[rr], rs = rs_s[rr];
      short8v o;
      #pragma unroll
      for (int j = 0; j < 8; ++j)
        o[j] = f2bf((bf2f(v[j]) - mu) * rs * gg[j] + ee[j]);
      *(short8v*)&Vlds[rr][chunk * 8] = o;
    }
  }
  __syncthreads();
  // write Vt swizzled: row = d, chunk c8 -> c8 ^ (d&7) within this 64-c window
  {
    const int h = tid >> 6, d = tid & 63;
    short* dst = Vtg + ((size_t)(b*H_ + h) * D_ + d) * C_ + c0;
    #pragma unroll
    for (int c8 = 0; c8 < 8; ++c8) {
      short8v vv;
      #pragma unroll
      for (int j = 0; j < 8; ++j) vv[j] = Vlds[c8*8 + j][tid];
      *(short8v*)(dst + ((c8 ^ (d&7)) << 3)) = vv;
    }
  }
}

// ---- MFMA flash attention: 8 waves / 128 q-rows, triple-buffered K/V with a
//      SINGLE barrier per kt; XCD-friendly grid (bh = blockIdx.x). ----
__global__ __launch_bounds__(512, 4) void attn_mfma_kernel(
    const short* __restrict__ Qg, const short* __restrict__ Kg,
    const short* __restrict__ Vtg, short* __restrict__ ob) {
  __shared__ short Ks[3][4096];     // [buf][64 keys x 64 d], swizzled image
  __shared__ short Vs[3][4096];     // [buf][64 d x 64 keys], swizzled image
  __shared__ short Ps[8][1024];     // per-wave P tile [16 q][64 keys], swizzled
  const int tid = threadIdx.x;
  const int w  = tid >> 6;          // 0..7
  const int l  = tid & 63, lo = l & 15, hi = l >> 4;
  const int sw = lo & 7;
  const int bh = blockIdx.x, qt = blockIdx.y;   // bh-major: same-bh -> same XCD
  const size_t hd = (size_t)bh * (C_ * D_);
  const int q0 = qt * 128 + w * 16;

  const short8v bq0 = *(const short8v*)(Qg + hd + (size_t)(q0+lo)*D_ + hi*8);
  const short8v bq1 = *(const short8v*)(Qg + hd + (size_t)(q0+lo)*D_ + 32 + hi*8);

  // staging geometry: wave w DMAs segment w (1KB) of K and of V per tile
  const short* Ktile = Kg + hd;
  const short* Vrow  = Vtg + hd;
  const int kOff = w*512 + l*8;
  const size_t vOff = (size_t)(w*8 + (l>>3)) * C_ + (l&7)*8;

  float mrun = -3.0e38f, lrun = 0.f;     // log2-domain running max
  f32x4 Oacc[4] = {{0,0,0,0},{0,0,0,0},{0,0,0,0},{0,0,0,0}};
  short* Pw = &Ps[w][0];

  gll16(Ktile + kOff, &Ks[0][w*512]);
  gll16(Vrow + vOff,  &Vs[0][w*512]);

  int cur = 0, nxt = 1;
  for (int kt = 0; kt < 32; ++kt) {
    // my loads for buf[cur] (issued last iter / prologue) have landed:
    asm volatile("s_waitcnt vmcnt(0)" ::: "memory");
    // all waves: their loads landed AND they finished compute(kt-1);
    // buf[nxt] was last read at kt-2 -> safe to overwrite after this barrier.
    __builtin_amdgcn_s_barrier();
    if (kt != 31) {
      const short* kn = Ktile + (size_t)(kt+1) * 4096;
      const short* vn = Vrow  + (size_t)(kt+1) * 64;
      gll16(kn + kOff, &Ks[nxt][w*512]);
      gll16(vn + vOff, &Vs[nxt][w*512]);
    }
    const short* Kc = &Ks[cur][0];
    const short* Vc = &Vs[cur][0];

    f32x4 st[4];
    __builtin_amdgcn_s_setprio(1);
    #pragma unroll
    for (int mt = 0; mt < 4; ++mt) {
      short8v ka = *(const short8v*)&Kc[(mt*16 + lo)*64 + ((hi ^ sw) << 3)];
      short8v kb = *(const short8v*)&Kc[(mt*16 + lo)*64 + (((4 + hi) ^ sw) << 3)];
      f32x4 z = {0.f, 0.f, 0.f, 0.f};
      z      = __builtin_amdgcn_mfma_f32_16x16x32_bf16(ka, bq0, z, 0, 0, 0);
      st[mt] = __builtin_amdgcn_mfma_f32_16x16x32_bf16(kb, bq1, z, 0, 0, 0);
    }
    __builtin_amdgcn_s_setprio(0);

    // online softmax, log2 domain; tree reductions (max3-fusable)
    float ps[16];
    #pragma unroll
    for (int mt = 0; mt < 4; ++mt)
      #pragma unroll
      for (int r = 0; r < 4; ++r) ps[mt*4 + r] = st[mt][r];
    float t0 = fmaxf(fmaxf(ps[0], ps[1]), ps[2]);
    float t1 = fmaxf(fmaxf(ps[3], ps[4]), ps[5]);
    float t2 = fmaxf(fmaxf(ps[6], ps[7]), ps[8]);
    float t3 = fmaxf(fmaxf(ps[9], ps[10]), ps[11]);
    float t4 = fmaxf(fmaxf(ps[12], ps[13]), ps[14]);
    float tmax = fmaxf(fmaxf(fmaxf(t0, t1), t2), fmaxf(fmaxf(t3, t4), ps[15]));
    tmax = fmaxf(tmax, __shfl_xor(tmax, 16));
    tmax = fmaxf(tmax, __shfl_xor(tmax, 32));
    if (__any(tmax > mrun + 11.5415603f)) {
      float mnew = fmaxf(mrun, tmax);
      float corr = exp2x(mrun - mnew);
      mrun = mnew;
      lrun *= corr;
      float cc[4];
      #pragma unroll
      for (int r = 0; r < 4; ++r) cc[r] = __shfl(corr, hi*4 + r);
      #pragma unroll
      for (int nt = 0; nt < 4; ++nt)
        #pragma unroll
        for (int r = 0; r < 4; ++r) Oacc[nt][r] *= cc[r];
    }
    #pragma unroll
    for (int i = 0; i < 16; ++i) ps[i] = exp2x(ps[i] - mrun);  // <= 2^11.54
    float s0 = (ps[0]+ps[1]) + (ps[2]+ps[3]);
    float s1 = (ps[4]+ps[5]) + (ps[6]+ps[7]);
    float s2 = (ps[8]+ps[9]) + (ps[10]+ps[11]);
    float s3 = (ps[12]+ps[13]) + (ps[14]+ps[15]);
    float ll = (s0 + s1) + (s2 + s3);
    ll += __shfl_xor(ll, 16);
    ll += __shfl_xor(ll, 32);
    lrun += ll;

    // P -> bf16 via v_cvt_pk, per-wave swizzled LDS
    #pragma unroll
    for (int mt = 0; mt < 4; ++mt) {
      uint2 pk;
      pk.x = cvtpk(ps[mt*4+0], ps[mt*4+1]);
      pk.y = cvtpk(ps[mt*4+2], ps[mt*4+3]);
      *(uint2*)&Pw[lo*64 + ((((mt<<1) + (hi>>1)) ^ sw) << 3) + ((hi&1) << 2)] = pk;
    }
    asm volatile("s_waitcnt lgkmcnt(0)" ::: "memory");   // same-wave P RAW

    short8v pa0 = *(short8v*)&Pw[lo*64 + ((hi ^ sw) << 3)];
    short8v pa1 = *(short8v*)&Pw[lo*64 + (((4 + hi) ^ sw) << 3)];
    __builtin_amdgcn_s_setprio(1);
    #pragma unroll
    for (int nt = 0; nt < 4; ++nt) {
      short8v vb0 = *(const short8v*)&Vc[(nt*16 + lo)*64 + ((hi ^ sw) << 3)];
      short8v vb1 = *(const short8v*)&Vc[(nt*16 + lo)*64 + (((4 + hi) ^ sw) << 3)];
      Oacc[nt] = __builtin_amdgcn_mfma_f32_16x16x32_bf16(pa0, vb0, Oacc[nt], 0,0,0);
      Oacc[nt] = __builtin_amdgcn_mfma_f32_16x16x32_bf16(pa1, vb1, Oacc[nt], 0,0,0);
    }
    __builtin_amdgcn_s_setprio(0);
    cur = nxt;
    nxt = (nxt == 2) ? 0 : nxt + 1;
  }

  float linv = 1.f / lrun;
  float li[4];
  #pragma unroll
  for (int r = 0; r < 4; ++r) li[r] = __shfl(linv, hi*4 + r);
  const int b = bh >> 2, h = bh & 3;
  short* obp = ob + ((size_t)b * C_ + q0) * L_ + h * D_;
  #pragma unroll
  for (int nt = 0; nt < 4; ++nt)
    #pragma unroll
    for (int r = 0; r < 4; ++r)
      obp[(hi*4 + r) * L_ + nt*16 + lo] = f2bf(Oacc[nt][r] * li[r]);
}

// ---- GEMM2 + LN2 + residual, fused. BM=64, full N=256 per block ----
__global__ __launch_bounds__(256) void gemm2_ln_mfma_kernel(
    const short* __restrict__ ob, const short* __restrict__ W2t,
    const float* __restrict__ b2, const float* __restrict__ g2,
    const float* __restrict__ be2, const float* __restrict__ x,
    float* __restrict__ out) {
  __shared__ short As[64*72];
  __shared__ short Bs[256*72];
  __shared__ float2 red[2][2][32];
  const int tid = threadIdx.x;
  const int w = tid >> 6, l = tid & 63, lo = l & 15, hi = l >> 4;
  const int wr = w >> 1, wc = w & 1;
  const int m0 = blockIdx.x * 64;

  f32x4 acc[2][8];
  #pragma unroll
  for (int m = 0; m < 2; ++m)
    #pragma unroll
    for (int n = 0; n < 8; ++n) acc[m][n] = (f32x4){0.f,0.f,0.f,0.f};

  for (int kt = 0; kt < 4; ++kt) {
    __syncthreads();
    #pragma unroll
    for (int i = 0; i < 2; ++i) {
      int id = tid + i * 256;
      int row = id >> 3, k8 = (id & 7) * 8;
      *(short8v*)&As[row*72 + k8] =
          *(const short8v*)(ob + (size_t)(m0 + row) * 256 + kt*64 + k8);
    }
    #pragma unroll
    for (int i = 0; i < 8; ++i) {
      int id = tid + i * 256;
      int row = id >> 3, k8 = (id & 7) * 8;
      *(short8v*)&Bs[row*72 + k8] =
          *(const short8v*)(W2t + (size_t)row * 256 + kt*64 + k8);
    }
    __syncthreads();
    #pragma unroll
    for (int kk = 0; kk < 2; ++kk) {
      short8v af[2], bf[8];
      #pragma unroll
      for (int m = 0; m < 2; ++m)
        af[m] = *(short8v*)&As[(wr*32 + m*16 + lo)*72 + kk*32 + hi*8];
      #pragma unroll
      for (int n = 0; n < 8; ++n)
        bf[n] = *(short8v*)&Bs[(wc*128 + n*16 + lo)*72 + kk*32 + hi*8];
      #pragma unroll
      for (int m = 0; m < 2; ++m)
        #pragma unroll
        for (int n = 0; n < 8; ++n)
          acc[m][n] = __builtin_amdgcn_mfma_f32_16x16x32_bf16(af[m], bf[n], acc[m][n], 0,0,0);
    }
  }

  float bb[8], gg[8], ee[8];
  #pragma unroll
  for (int n = 0; n < 8; ++n) {
    int col = wc*128 + n*16 + lo;
    bb[n] = b2[col]; gg[n] = g2[col]; ee[n] = be2[col];
  }
  float ps[2][4], pq[2][4];
  #pragma unroll
  for (int m = 0; m < 2; ++m)
    #pragma unroll
    for (int r = 0; r < 4; ++r) {
      float s = 0.f, s2 = 0.f;
      #pragma unroll
      for (int n = 0; n < 8; ++n) {
        float v = acc[m][n][r] + bb[n];
        acc[m][n][r] = v;
        s += v; s2 += v*v;
      }
      ps[m][r] = s; pq[m][r] = s2;
    }
  #pragma unroll
  for (int off = 1; off < 16; off <<= 1)
    #pragma unroll
    for (int m = 0; m < 2; ++m)
      #pragma unroll
      for (int r = 0; r < 4; ++r) {
        ps[m][r] += __shfl_xor(ps[m][r], off);
        pq[m][r] += __shfl_xor(pq[m][r], off);
      }
  if (lo == 0)
    #pragma unroll
    for (int m = 0; m < 2; ++m)
      #pragma unroll
      for (int r = 0; r < 4; ++r)
        red[wr][wc][m*16 + hi*4 + r] = make_float2(ps[m][r], pq[m][r]);
  __syncthreads();

  #pragma unroll
  for (int m = 0; m < 2; ++m)
    #pragma unroll
    for (int r = 0; r < 4; ++r) {
      float2 t0 = red[wr][0][m*16 + hi*4 + r];
      float2 t1 = red[wr][1][m*16 + hi*4 + r];
      float s = t0.x + t1.x, s2 = t0.y + t1.y;
      float mu  = s * (1.f / L_);
      float var = s2 * (1.f / L_) - mu * mu;
      float rs  = rsqrtf(var + 1e-5f);
      const int grow = m0 + wr*32 + m*16 + hi*4 + r;
      const float* xr = x + (size_t)grow * L_ + wc*128;
      float* orow = out + (size_t)grow * L_ + wc*128;
      #pragma unroll
      for (int n = 0; n < 8; ++n)
        orow[n*16 + lo] = (acc[m][n][r] - mu) * rs * gg[n] + ee[n] + xr[n*16 + lo];
    }
}

extern "C" void kernel_launch(void* const* d_in, const int* in_sizes, int n_in,
                              void* d_out, int out_size, void* d_ws, size_t ws_size,
                              hipStream_t stream) {
  const float* x   = (const float*)d_in[0];
  const float* W1  = (const float*)d_in[1];
  const float* b1  = (const float*)d_in[2];
  const float* g1  = (const float*)d_in[3];
  const float* be1 = (const float*)d_in[4];
  const float* W2  = (const float*)d_in[5];
  const float* b2  = (const float*)d_in[6];
  const float* g2  = (const float*)d_in[7];
  const float* be2 = (const float*)d_in[8];
  float* out = (float*)d_out;

  const size_t HDSZ = (size_t)B_ * H_ * C_ * D_;   // 4,194,304
  short* W1t = (short*)d_ws;          // [768][256] bf16
  short* W2t = W1t + (size_t)L_ * E_; // [256][256] bf16
  short* y1  = W2t + (size_t)L_ * L_; // [M][768] bf16
  short* Qg  = y1  + (size_t)M_ * E_; // [bh][c][64] (pre-scaled, log2 domain)
  short* Kg  = Qg  + HDSZ;            // [bh][c][64] swizzled
  short* Vtg = Kg  + HDSZ;            // [bh][64][c] swizzled
  short* obm = Vtg + HDSZ;            // [M][256] bf16

  transpose_w_kernel<<<dim3(8, 24), 256, 0, stream>>>(W1, W1t, L_, E_);
  transpose_w_kernel<<<dim3(8, 8),  256, 0, stream>>>(W2, W2t, L_, L_);
  gemm1_mfma_kernel<<<dim3(M_ / 128, E_ / 128), 256, 0, stream>>>(x, W1t, b1, y1);
  ln1_kernel<<<M_ / 64, 256, 0, stream>>>(y1, g1, be1, Qg, Kg, Vtg);
  attn_mfma_kernel<<<dim3(32, C_ / 128), 512, 0, stream>>>(Qg, Kg, Vtg, obm);
  gemm2_ln_mfma_kernel<<<M_ / 64, 256, 0, stream>>>(obm, W2t, b2, g2, be2, x, out);
}

// Round 8
// 112.900 us; speedup vs baseline: 12.1892x; 1.0286x over previous
//
#include <hip/hip_runtime.h>
#include <hip/hip_bf16.h>

#define B_ 8
#define C_ 2048
#define L_ 256
#define E_ 768
#define H_ 4
#define D_ 64
#define M_ (B_*C_)   // 16384 rows

typedef __attribute__((ext_vector_type(8))) short short8v;   // 8 bf16 (4 VGPR) MFMA A/B frag
typedef __attribute__((ext_vector_type(4))) short short4v;   // 8B packed store
typedef __attribute__((ext_vector_type(4))) float f32x4;     // MFMA C/D frag

__device__ __forceinline__ short f2bf(float f) {             // f32 -> bf16 RNE
  union { float f; unsigned u; } v; v.f = f;
  unsigned r = v.u + 0x7FFFu + ((v.u >> 16) & 1u);
  return (short)(r >> 16);
}
__device__ __forceinline__ float bf2f(short s) {
  union { unsigned u; float f; } v; v.u = ((unsigned)(unsigned short)s) << 16;
  return v.f;
}
// two f32 -> packed bf16x2 in one VALU op (gfx950; no builtin, m240)
__device__ __forceinline__ unsigned cvtpk(float a, float b) {
  unsigned r;
  asm("v_cvt_pk_bf16_f32 %0, %1, %2" : "=v"(r) : "v"(a), "v"(b));
  return r;
}
__device__ __forceinline__ float exp2x(float x) {            // 2^x, single v_exp_f32
  float r;
  asm("v_exp_f32 %0, %1" : "=v"(r) : "v"(x));
  return r;
}

// async global->LDS, 16B per lane; LDS dest = uniform base + lane*16 (m104)
__device__ __forceinline__ void gll16(const void* g, void* l) {
  __builtin_amdgcn_global_load_lds(
      (const __attribute__((address_space(1))) unsigned int*)g,
      (__attribute__((address_space(3))) unsigned int*)l, 16, 0, 0);
}

// ---- prep: W f32 [K][N] -> Wt bf16 [N][K] via 32x32 LDS tiles ----
__global__ __launch_bounds__(256) void transpose_w_kernel(const float* __restrict__ W,
                                                          short* __restrict__ Wt,
                                                          int K, int N) {
  __shared__ float ld[32][33];
  const int k0 = blockIdx.x * 32, n0 = blockIdx.y * 32;
  const int tx = threadIdx.x & 31, ty = threadIdx.x >> 5;
  #pragma unroll
  for (int j = 0; j < 4; ++j)
    ld[ty + j*8][tx] = W[(size_t)(k0 + ty + j*8) * N + n0 + tx];
  __syncthreads();
  const int r  = threadIdx.x >> 3;
  const int c0 = (threadIdx.x & 7) * 4;
  short4v o;
  o[0]=f2bf(ld[c0+0][r]); o[1]=f2bf(ld[c0+1][r]);
  o[2]=f2bf(ld[c0+2][r]); o[3]=f2bf(ld[c0+3][r]);
  *(short4v*)(Wt + (size_t)(n0 + r) * K + k0 + c0) = o;
}

// ---- GEMM1: y1[M][768] = x[M][256] @ W1 (+b1); x converted in staging ----
__global__ __launch_bounds__(256) void gemm1_mfma_kernel(
    const float* __restrict__ x, const short* __restrict__ W1t,
    const float* __restrict__ b1, short* __restrict__ y1) {
  __shared__ short As[128*72];
  __shared__ short Bs[128*72];
  const int tid = threadIdx.x;
  const int w = tid >> 6, l = tid & 63, lo = l & 15, hi = l >> 4;
  const int wr = w >> 1, wc = w & 1;
  const int m0 = blockIdx.x * 128, n0 = blockIdx.y * 128;

  f32x4 acc[4][4];
  #pragma unroll
  for (int m = 0; m < 4; ++m)
    #pragma unroll
    for (int n = 0; n < 4; ++n) acc[m][n] = (f32x4){0.f,0.f,0.f,0.f};

  for (int kt = 0; kt < 4; ++kt) {
    __syncthreads();
    #pragma unroll
    for (int i = 0; i < 4; ++i) {
      int id = tid + i * 256;
      int row = id >> 3, k8 = (id & 7) * 8;
      const float* ap = x + (size_t)(m0 + row) * 256 + kt*64 + k8;
      float4 a0 = ((const float4*)ap)[0], a1 = ((const float4*)ap)[1];
      uint4 pk;
      pk.x = cvtpk(a0.x, a0.y); pk.y = cvtpk(a0.z, a0.w);
      pk.z = cvtpk(a1.x, a1.y); pk.w = cvtpk(a1.z, a1.w);
      *(uint4*)&As[row*72 + k8] = pk;
      *(short8v*)&Bs[row*72 + k8] =
          *(const short8v*)(W1t + (size_t)(n0 + row) * 256 + kt*64 + k8);
    }
    __syncthreads();
    #pragma unroll
    for (int kk = 0; kk < 2; ++kk) {
      short8v af[4], bf[4];
      #pragma unroll
      for (int m = 0; m < 4; ++m)
        af[m] = *(short8v*)&As[(wr*64 + m*16 + lo)*72 + kk*32 + hi*8];
      #pragma unroll
      for (int n = 0; n < 4; ++n)
        bf[n] = *(short8v*)&Bs[(wc*64 + n*16 + lo)*72 + kk*32 + hi*8];
      #pragma unroll
      for (int m = 0; m < 4; ++m)
        #pragma unroll
        for (int n = 0; n < 4; ++n)
          acc[m][n] = __builtin_amdgcn_mfma_f32_16x16x32_bf16(af[m], bf[n], acc[m][n], 0,0,0);
    }
  }

  float bb[4];
  #pragma unroll
  for (int n = 0; n < 4; ++n) bb[n] = b1[n0 + wc*64 + n*16 + lo];
  #pragma unroll
  for (int m = 0; m < 4; ++m) {
    const int gr = m0 + wr*64 + m*16 + hi*4;
    #pragma unroll
    for (int r = 0; r < 4; ++r) {
      short* yp = y1 + (size_t)(gr + r) * E_ + n0 + wc*64;
      #pragma unroll
      for (int n = 0; n < 4; ++n)
        yp[n*16 + lo] = f2bf(acc[m][n][r] + bb[n]);
    }
  }
}

// ---- LN1: y1 -> Q (x 0.125*log2e, linear), K + Vt PRE-SWIZZLED for attn ----
__global__ __launch_bounds__(256) void ln1_kernel(
    const short* __restrict__ y1, const float* __restrict__ g1,
    const float* __restrict__ be1,
    short* __restrict__ Qg, short* __restrict__ Kg, short* __restrict__ Vtg) {
  __shared__ float mu_s[64], rs_s[64];
  __shared__ short Vlds[64][264];
  const int tid = threadIdx.x;
  const int w = tid >> 6, l = tid & 63;
  const int b = blockIdx.x >> 5;
  const int c0 = (blockIdx.x & 31) * 64;
  const size_t rowbase = (size_t)b * C_ + c0;

  for (int rr = w*16; rr < w*16 + 16; ++rr) {
    const short* yr = y1 + (rowbase + rr) * E_ + l * 12;
    float s = 0.f, s2 = 0.f;
    #pragma unroll
    for (int j = 0; j < 3; ++j) {
      short4v v = *(const short4v*)(yr + j*4);
      #pragma unroll
      for (int t = 0; t < 4; ++t) { float f = bf2f(v[t]); s += f; s2 += f*f; }
    }
    #pragma unroll
    for (int off = 1; off < 64; off <<= 1) {
      s  += __shfl_xor(s, off);
      s2 += __shfl_xor(s2, off);
    }
    if (l == 0) {
      float mu = s * (1.f / E_);
      float var = s2 * (1.f / E_) - mu * mu;
      mu_s[rr] = mu;
      rs_s[rr] = rsqrtf(var + 1e-5f);
    }
  }
  __syncthreads();

  // emit Q (linear, log2-domain scale) and K (swizzled)
  {
    const int chunk = tid & 63, e0 = chunk * 8;
    float gg[8], ee[8];
    #pragma unroll
    for (int j = 0; j < 8; ++j) { gg[j] = g1[e0+j]; ee[j] = be1[e0+j]; }
    const int isQ = (e0 < 256);
    const int eb  = isQ ? e0 : e0 - 256;
    const int h = eb >> 6, d0 = eb & 63;
    short* dstQ = Qg + ((size_t)(b*H_ + h) * C_ + c0) * D_ + d0;
    short* dstK = Kg + ((size_t)(b*H_ + h) * C_ + c0) * D_;
    const float qs = isQ ? 0.18033688011f : 1.f;   // 0.125 * log2(e)
    for (int rg = 0; rg < 16; ++rg) {
      int rr = rg*4 + (tid >> 6);
      short8v v = *(const short8v*)(y1 + (rowbase + rr) * E_ + e0);
      float mu = mu_s[rr], rs = rs_s[rr];
      short8v o;
      #pragma unroll
      for (int j = 0; j < 8; ++j)
        o[j] = f2bf(((bf2f(v[j]) - mu) * rs * gg[j] + ee[j]) * qs);
      if (isQ) *(short8v*)(dstQ + (size_t)rr * D_) = o;
      else     *(short8v*)(dstK + (size_t)rr * D_ + ((((d0>>3) ^ (rr&7)) << 3))) = o;
    }
  }
  // emit V into LDS
  {
    const int chunk = tid & 31, e0 = 512 + chunk * 8;
    float gg[8], ee[8];
    #pragma unroll
    for (int j = 0; j < 8; ++j) { gg[j] = g1[e0+j]; ee[j] = be1[e0+j]; }
    for (int rg = 0; rg < 8; ++rg) {
      int rr = rg*8 + (tid >> 5);
      short8v v = *(const short8v*)(y1 + (rowbase + rr) * E_ + e0);
      float mu = mu_s[rr], rs = rs_s[rr];
      short8v o;
      #pragma unroll
      for (int j = 0; j < 8; ++j)
        o[j] = f2bf((bf2f(v[j]) - mu) * rs * gg[j] + ee[j]);
      *(short8v*)&Vlds[rr][chunk * 8] = o;
    }
  }
  __syncthreads();
  // write Vt swizzled: row = d, chunk c8 -> c8 ^ (d&7) within this 64-c window
  {
    const int h = tid >> 6, d = tid & 63;
    short* dst = Vtg + ((size_t)(b*H_ + h) * D_ + d) * C_ + c0;
    #pragma unroll
    for (int c8 = 0; c8 < 8; ++c8) {
      short8v vv;
      #pragma unroll
      for (int j = 0; j < 8; ++j) vv[j] = Vlds[c8*8 + j][tid];
      *(short8v*)(dst + ((c8 ^ (d&7)) << 3)) = vv;
    }
  }
}

// ---- MFMA flash attention: 8 waves / 128 q-rows, triple-buffered K/V, single
//      barrier per kt, XCD grid. R7: exp-first softmax (max tree + shfls off
//      the critical path), per-lane deferred l-sum (epilogue reduction). ----
__global__ __launch_bounds__(512, 4) void attn_mfma_kernel(
    const short* __restrict__ Qg, const short* __restrict__ Kg,
    const short* __restrict__ Vtg, short* __restrict__ ob) {
  __shared__ short Ks[3][4096];     // [buf][64 keys x 64 d], swizzled image
  __shared__ short Vs[3][4096];     // [buf][64 d x 64 keys], swizzled image
  __shared__ short Ps[8][1024];     // per-wave P tile [16 q][64 keys], swizzled
  const int tid = threadIdx.x;
  const int w  = tid >> 6;          // 0..7
  const int l  = tid & 63, lo = l & 15, hi = l >> 4;
  const int sw = lo & 7;
  const int bh = blockIdx.x, qt = blockIdx.y;   // bh-major: same-bh -> same XCD
  const size_t hd = (size_t)bh * (C_ * D_);
  const int q0 = qt * 128 + w * 16;

  const short8v bq0 = *(const short8v*)(Qg + hd + (size_t)(q0+lo)*D_ + hi*8);
  const short8v bq1 = *(const short8v*)(Qg + hd + (size_t)(q0+lo)*D_ + 32 + hi*8);

  // staging geometry: wave w DMAs segment w (1KB) of K and of V per tile
  const short* Ktile = Kg + hd;
  const short* Vrow  = Vtg + hd;
  const int kOff = w*512 + l*8;
  const size_t vOff = (size_t)(w*8 + (l>>3)) * C_ + (l&7)*8;

  // mrun = -30: tile 0 always rescales cleanly (corr = 2^(-30-mnew), no inf)
  float mrun = -30.f, lrun = 0.f;        // lrun: PER-LANE partial (16 keys)
  f32x4 Oacc[4] = {{0,0,0,0},{0,0,0,0},{0,0,0,0},{0,0,0,0}};
  short* Pw = &Ps[w][0];

  gll16(Ktile + kOff, &Ks[0][w*512]);
  gll16(Vrow + vOff,  &Vs[0][w*512]);

  int cur = 0, nxt = 1;
  for (int kt = 0; kt < 32; ++kt) {
    asm volatile("s_waitcnt vmcnt(0)" ::: "memory");
    __builtin_amdgcn_s_barrier();        // buf[cur] full; buf[nxt] free (read kt-2)
    if (kt != 31) {
      const short* kn = Ktile + (size_t)(kt+1) * 4096;
      const short* vn = Vrow  + (size_t)(kt+1) * 64;
      gll16(kn + kOff, &Ks[nxt][w*512]);
      gll16(vn + vOff, &Vs[nxt][w*512]);
    }
    const short* Kc = &Ks[cur][0];
    const short* Vc = &Vs[cur][0];

    f32x4 st[4];
    __builtin_amdgcn_s_setprio(1);
    #pragma unroll
    for (int mt = 0; mt < 4; ++mt) {
      short8v ka = *(const short8v*)&Kc[(mt*16 + lo)*64 + ((hi ^ sw) << 3)];
      short8v kb = *(const short8v*)&Kc[(mt*16 + lo)*64 + (((4 + hi) ^ sw) << 3)];
      f32x4 z = {0.f, 0.f, 0.f, 0.f};
      z      = __builtin_amdgcn_mfma_f32_16x16x32_bf16(ka, bq0, z, 0, 0, 0);
      st[mt] = __builtin_amdgcn_mfma_f32_16x16x32_bf16(kb, bq1, z, 0, 0, 0);
    }
    __builtin_amdgcn_s_setprio(0);

    // exp-first: ps uses current mrun (defer-max); max tree + shfls overlap
    float ps[16];
    #pragma unroll
    for (int mt = 0; mt < 4; ++mt)
      #pragma unroll
      for (int r = 0; r < 4; ++r)
        ps[mt*4 + r] = exp2x(st[mt][r] - mrun);
    float t0 = fmaxf(fmaxf(st[0][0], st[0][1]), st[0][2]);
    float t1 = fmaxf(fmaxf(st[0][3], st[1][0]), st[1][1]);
    float t2 = fmaxf(fmaxf(st[1][2], st[1][3]), st[2][0]);
    float t3 = fmaxf(fmaxf(st[2][1], st[2][2]), st[2][3]);
    float t4 = fmaxf(fmaxf(st[3][0], st[3][1]), st[3][2]);
    float tmax = fmaxf(fmaxf(fmaxf(t0, t1), t2), fmaxf(fmaxf(t3, t4), st[3][3]));
    tmax = fmaxf(tmax, __shfl_xor(tmax, 16));
    tmax = fmaxf(tmax, __shfl_xor(tmax, 32));
    if (__any(tmax > mrun + 11.5415603f)) {     // rare rescale: fix-up ps too
      float mnew = fmaxf(mrun, tmax);
      float corr = exp2x(mrun - mnew);
      mrun = mnew;
      lrun *= corr;
      #pragma unroll
      for (int i = 0; i < 16; ++i) ps[i] *= corr;
      float cc[4];
      #pragma unroll
      for (int r = 0; r < 4; ++r) cc[r] = __shfl(corr, hi*4 + r);
      #pragma unroll
      for (int nt = 0; nt < 4; ++nt)
        #pragma unroll
        for (int r = 0; r < 4; ++r) Oacc[nt][r] *= cc[r];
    }
    // per-lane partial row-sum; cross-lane reduce deferred to epilogue
    float s0 = (ps[0]+ps[1]) + (ps[2]+ps[3]);
    float s1 = (ps[4]+ps[5]) + (ps[6]+ps[7]);
    float s2 = (ps[8]+ps[9]) + (ps[10]+ps[11]);
    float s3 = (ps[12]+ps[13]) + (ps[14]+ps[15]);
    lrun += (s0 + s1) + (s2 + s3);

    // P -> bf16 via v_cvt_pk, per-wave swizzled LDS
    #pragma unroll
    for (int mt = 0; mt < 4; ++mt) {
      uint2 pk;
      pk.x = cvtpk(ps[mt*4+0], ps[mt*4+1]);
      pk.y = cvtpk(ps[mt*4+2], ps[mt*4+3]);
      *(uint2*)&Pw[lo*64 + ((((mt<<1) + (hi>>1)) ^ sw) << 3) + ((hi&1) << 2)] = pk;
    }
    asm volatile("s_waitcnt lgkmcnt(0)" ::: "memory");   // same-wave P RAW

    short8v pa0 = *(short8v*)&Pw[lo*64 + ((hi ^ sw) << 3)];
    short8v pa1 = *(short8v*)&Pw[lo*64 + (((4 + hi) ^ sw) << 3)];
    __builtin_amdgcn_s_setprio(1);
    #pragma unroll
    for (int nt = 0; nt < 4; ++nt) {
      short8v vb0 = *(const short8v*)&Vc[(nt*16 + lo)*64 + ((hi ^ sw) << 3)];
      short8v vb1 = *(const short8v*)&Vc[(nt*16 + lo)*64 + (((4 + hi) ^ sw) << 3)];
      Oacc[nt] = __builtin_amdgcn_mfma_f32_16x16x32_bf16(pa0, vb0, Oacc[nt], 0,0,0);
      Oacc[nt] = __builtin_amdgcn_mfma_f32_16x16x32_bf16(pa1, vb1, Oacc[nt], 0,0,0);
    }
    __builtin_amdgcn_s_setprio(0);
    cur = nxt;
    nxt = (nxt == 2) ? 0 : nxt + 1;
  }

  // epilogue: cross-lane l reduction (deferred from loop)
  lrun += __shfl_xor(lrun, 16);
  lrun += __shfl_xor(lrun, 32);
  float linv = 1.f / lrun;
  float li[4];
  #pragma unroll
  for (int r = 0; r < 4; ++r) li[r] = __shfl(linv, hi*4 + r);
  const int b = bh >> 2, h = bh & 3;
  short* obp = ob + ((size_t)b * C_ + q0) * L_ + h * D_;
  #pragma unroll
  for (int nt = 0; nt < 4; ++nt)
    #pragma unroll
    for (int r = 0; r < 4; ++r)
      obp[(hi*4 + r) * L_ + nt*16 + lo] = f2bf(Oacc[nt][r] * li[r]);
}

// ---- GEMM2 + LN2 + residual, fused. BM=64, full N=256 per block ----
__global__ __launch_bounds__(256) void gemm2_ln_mfma_kernel(
    const short* __restrict__ ob, const short* __restrict__ W2t,
    const float* __restrict__ b2, const float* __restrict__ g2,
    const float* __restrict__ be2, const float* __restrict__ x,
    float* __restrict__ out) {
  __shared__ short As[64*72];
  __shared__ short Bs[256*72];
  __shared__ float2 red[2][2][32];
  const int tid = threadIdx.x;
  const int w = tid >> 6, l = tid & 63, lo = l & 15, hi = l >> 4;
  const int wr = w >> 1, wc = w & 1;
  const int m0 = blockIdx.x * 64;

  f32x4 acc[2][8];
  #pragma unroll
  for (int m = 0; m < 2; ++m)
    #pragma unroll
    for (int n = 0; n < 8; ++n) acc[m][n] = (f32x4){0.f,0.f,0.f,0.f};

  for (int kt = 0; kt < 4; ++kt) {
    __syncthreads();
    #pragma unroll
    for (int i = 0; i < 2; ++i) {
      int id = tid + i * 256;
      int row = id >> 3, k8 = (id & 7) * 8;
      *(short8v*)&As[row*72 + k8] =
          *(const short8v*)(ob + (size_t)(m0 + row) * 256 + kt*64 + k8);
    }
    #pragma unroll
    for (int i = 0; i < 8; ++i) {
      int id = tid + i * 256;
      int row = id >> 3, k8 = (id & 7) * 8;
      *(short8v*)&Bs[row*72 + k8] =
          *(const short8v*)(W2t + (size_t)row * 256 + kt*64 + k8);
    }
    __syncthreads();
    #pragma unroll
    for (int kk = 0; kk < 2; ++kk) {
      short8v af[2], bf[8];
      #pragma unroll
      for (int m = 0; m < 2; ++m)
        af[m] = *(short8v*)&As[(wr*32 + m*16 + lo)*72 + kk*32 + hi*8];
      #pragma unroll
      for (int n = 0; n < 8; ++n)
        bf[n] = *(short8v*)&Bs[(wc*128 + n*16 + lo)*72 + kk*32 + hi*8];
      #pragma unroll
      for (int m = 0; m < 2; ++m)
        #pragma unroll
        for (int n = 0; n < 8; ++n)
          acc[m][n] = __builtin_amdgcn_mfma_f32_16x16x32_bf16(af[m], bf[n], acc[m][n], 0,0,0);
    }
  }

  float bb[8], gg[8], ee[8];
  #pragma unroll
  for (int n = 0; n < 8; ++n) {
    int col = wc*128 + n*16 + lo;
    bb[n] = b2[col]; gg[n] = g2[col]; ee[n] = be2[col];
  }
  float ps[2][4], pq[2][4];
  #pragma unroll
  for (int m = 0; m < 2; ++m)
    #pragma unroll
    for (int r = 0; r < 4; ++r) {
      float s = 0.f, s2 = 0.f;
      #pragma unroll
      for (int n = 0; n < 8; ++n) {
        float v = acc[m][n][r] + bb[n];
        acc[m][n][r] = v;
        s += v; s2 += v*v;
      }
      ps[m][r] = s; pq[m][r] = s2;
    }
  #pragma unroll
  for (int off = 1; off < 16; off <<= 1)
    #pragma unroll
    for (int m = 0; m < 2; ++m)
      #pragma unroll
      for (int r = 0; r < 4; ++r) {
        ps[m][r] += __shfl_xor(ps[m][r], off);
        pq[m][r] += __shfl_xor(pq[m][r], off);
      }
  if (lo == 0)
    #pragma unroll
    for (int m = 0; m < 2; ++m)
      #pragma unroll
      for (int r = 0; r < 4; ++r)
        red[wr][wc][m*16 + hi*4 + r] = make_float2(ps[m][r], pq[m][r]);
  __syncthreads();

  #pragma unroll
  for (int m = 0; m < 2; ++m)
    #pragma unroll
    for (int r = 0; r < 4; ++r) {
      float2 t0 = red[wr][0][m*16 + hi*4 + r];
      float2 t1 = red[wr][1][m*16 + hi*4 + r];
      float s = t0.x + t1.x, s2 = t0.y + t1.y;
      float mu  = s * (1.f / L_);
      float var = s2 * (1.f / L_) - mu * mu;
      float rs  = rsqrtf(var + 1e-5f);
      const int grow = m0 + wr*32 + m*16 + hi*4 + r;
      const float* xr = x + (size_t)grow * L_ + wc*128;
      float* orow = out + (size_t)grow * L_ + wc*128;
      #pragma unroll
      for (int n = 0; n < 8; ++n)
        orow[n*16 + lo] = (acc[m][n][r] - mu) * rs * gg[n] + ee[n] + xr[n*16 + lo];
    }
}

extern "C" void kernel_launch(void* const* d_in, const int* in_sizes, int n_in,
                              void* d_out, int out_size, void* d_ws, size_t ws_size,
                              hipStream_t stream) {
  const float* x   = (const float*)d_in[0];
  const float* W1  = (const float*)d_in[1];
  const float* b1  = (const float*)d_in[2];
  const float* g1  = (const float*)d_in[3];
  const float* be1 = (const float*)d_in[4];
  const float* W2  = (const float*)d_in[5];
  const float* b2  = (const float*)d_in[6];
  const float* g2  = (const float*)d_in[7];
  const float* be2 = (const float*)d_in[8];
  float* out = (float*)d_out;

  const size_t HDSZ = (size_t)B_ * H_ * C_ * D_;   // 4,194,304
  short* W1t = (short*)d_ws;          // [768][256] bf16
  short* W2t = W1t + (size_t)L_ * E_; // [256][256] bf16
  short* y1  = W2t + (size_t)L_ * L_; // [M][768] bf16
  short* Qg  = y1  + (size_t)M_ * E_; // [bh][c][64] (pre-scaled, log2 domain)
  short* Kg  = Qg  + HDSZ;            // [bh][c][64] swizzled
  short* Vtg = Kg  + HDSZ;            // [bh][64][c] swizzled
  short* obm = Vtg + HDSZ;            // [M][256] bf16

  transpose_w_kernel<<<dim3(8, 24), 256, 0, stream>>>(W1, W1t, L_, E_);
  transpose_w_kernel<<<dim3(8, 8),  256, 0, stream>>>(W2, W2t, L_, L_);
  gemm1_mfma_kernel<<<dim3(M_ / 128, E_ / 128), 256, 0, stream>>>(x, W1t, b1, y1);
  ln1_kernel<<<M_ / 64, 256, 0, stream>>>(y1, g1, be1, Qg, Kg, Vtg);
  attn_mfma_kernel<<<dim3(32, C_ / 128), 512, 0, stream>>>(Qg, Kg, Vtg, obm);
  gemm2_ln_mfma_kernel<<<M_ / 64, 256, 0, stream>>>(obm, W2t, b2, g2, be2, x, out);
}